// Round 1
// baseline (1963.724 us; speedup 1.0000x reference)
//
#include <hip/hip_runtime.h>
#include <cstdint>
#include <cstddef>

#define E_DIM   1024
#define NHEADS  16
#define DHEAD   64
#define BATCH   8
#define SEQ     1024
#define MROWS   (BATCH*SEQ)   // 8192

// ---------------------------------------------------------------------------
// GEMM: C = A @ W^T + bias   (A: MxK row-major, W: NxK row-major)
// mode 0: out[m*N + n] = C
// mode 1: scatter to (B,H,T,Dh): out + z*M*N, index ((b*H+h)*T+t)*Dh + d
//         (z = blockIdx.z selects A in {A0,A1,A2} and W/bias slice z)
// 128x128 tile, BK=16, 256 threads, 8x8 micro-tile per thread.
// ---------------------------------------------------------------------------
__global__ __launch_bounds__(256)
void gemm_nt_kernel(const float* __restrict__ A0, const float* __restrict__ A1,
                    const float* __restrict__ A2, const float* __restrict__ W,
                    const float* __restrict__ bias, float* __restrict__ out,
                    int M, int N, int K, int mode)
{
    __shared__ float As[128][17];
    __shared__ float Ws[128][17];

    const int z = blockIdx.z;
    const float* A  = (z == 0) ? A0 : (z == 1) ? A1 : A2;
    const float* Wz = W    + (size_t)z * (size_t)N * K;
    const float* bz = bias + (size_t)z * N;
    float*     outz = out  + (size_t)z * (size_t)M * N;

    const int tid = threadIdx.x;
    const int tx = tid & 15, ty = tid >> 4;
    const int mBase = blockIdx.y * 128;
    const int nBase = blockIdx.x * 128;

    float acc[8][8];
#pragma unroll
    for (int i = 0; i < 8; ++i)
#pragma unroll
        for (int j = 0; j < 8; ++j) acc[i][j] = 0.f;

    for (int k0 = 0; k0 < K; k0 += 16) {
#pragma unroll
        for (int it = 0; it < 2; ++it) {
            int idx = tid + it * 256;           // 0..511
            int row = idx >> 2;                 // 0..127
            int c4  = (idx & 3) << 2;           // 0,4,8,12
            float4 av = *(const float4*)&A [(size_t)(mBase + row) * K + k0 + c4];
            As[row][c4+0] = av.x; As[row][c4+1] = av.y;
            As[row][c4+2] = av.z; As[row][c4+3] = av.w;
            float4 wv = *(const float4*)&Wz[(size_t)(nBase + row) * K + k0 + c4];
            Ws[row][c4+0] = wv.x; Ws[row][c4+1] = wv.y;
            Ws[row][c4+2] = wv.z; Ws[row][c4+3] = wv.w;
        }
        __syncthreads();
#pragma unroll
        for (int kk = 0; kk < 16; ++kk) {
            float a[8], b[8];
#pragma unroll
            for (int i = 0; i < 8; ++i) a[i] = As[ty*8+i][kk];
#pragma unroll
            for (int j = 0; j < 8; ++j) b[j] = Ws[tx*8+j][kk];
#pragma unroll
            for (int i = 0; i < 8; ++i)
#pragma unroll
                for (int j = 0; j < 8; ++j)
                    acc[i][j] += a[i] * b[j];
        }
        __syncthreads();
    }

    if (mode == 0) {
#pragma unroll
        for (int i = 0; i < 8; ++i) {
            int m = mBase + ty*8 + i;
#pragma unroll
            for (int j = 0; j < 8; ++j) {
                int n = nBase + tx*8 + j;
                outz[(size_t)m * N + n] = acc[i][j] + bz[n];
            }
        }
    } else {
#pragma unroll
        for (int i = 0; i < 8; ++i) {
            int m = mBase + ty*8 + i;
            int b = m >> 10, t = m & 1023;      // T = 1024
#pragma unroll
            for (int j = 0; j < 8; ++j) {
                int n = nBase + tx*8 + j;       // 0..1023 within slice
                int h = n >> 6, d = n & 63;     // Dh = 64
                outz[(((size_t)(b*NHEADS + h)) * SEQ + t) * DHEAD + d] = acc[i][j] + bz[n];
            }
        }
    }
}

// ---------------------------------------------------------------------------
// Flash-style attention. One block = one (b,h) and 64 query rows.
// 256 threads as 16x16; each thread owns a 4x4 S/P/O micro-tile.
// Online softmax (running m,l per row, state duplicated across the 16 tx).
// LDS: Qs[64][65], KPs[64][65] (K tile, then reused as P^T), Vs[64][64].
// ---------------------------------------------------------------------------
__global__ __launch_bounds__(256)
void attn_kernel(const float* __restrict__ q, const float* __restrict__ k,
                 const float* __restrict__ v, const float* __restrict__ attn_mask,
                 const unsigned char* __restrict__ kpad, float* __restrict__ ctx)
{
    __shared__ float Qs [64][65];
    __shared__ float KPs[64][65];   // K tile; after S-compute reused as P^T
    __shared__ float Vs [64][64];

    const int tid = threadIdx.x;
    const int tx = tid & 15, ty = tid >> 4;
    const int qt = blockIdx.x;                 // 0..15 query tile
    const int bh = blockIdx.y;                 // 0..127
    const int b = bh >> 4, h = bh & 15;

    const float* qbase = q + ((size_t)bh * SEQ + (size_t)qt * 64) * DHEAD;
    const float* kbase = k + (size_t)bh * SEQ * DHEAD;
    const float* vbase = v + (size_t)bh * SEQ * DHEAD;

    // load Q tile (64 x 64)
#pragma unroll
    for (int it = 0; it < 4; ++it) {
        int idx = tid + it * 256;              // 0..1023
        int row = idx >> 4;
        int c4  = (idx & 15) << 2;
        float4 qv = *(const float4*)&qbase[(size_t)row * DHEAD + c4];
        Qs[row][c4+0] = qv.x; Qs[row][c4+1] = qv.y;
        Qs[row][c4+2] = qv.z; Qs[row][c4+3] = qv.w;
    }

    float m_i[4], l_i[4], O[4][4];
#pragma unroll
    for (int ri = 0; ri < 4; ++ri) {
        m_i[ri] = -1e30f; l_i[ri] = 0.f;
#pragma unroll
        for (int ci = 0; ci < 4; ++ci) O[ri][ci] = 0.f;
    }

    for (int kt = 0; kt < 16; ++kt) {
        __syncthreads();   // prev iteration's reads of KPs/Vs done
#pragma unroll
        for (int it = 0; it < 4; ++it) {
            int idx = tid + it * 256;
            int row = idx >> 4;
            int c4  = (idx & 15) << 2;
            float4 kv = *(const float4*)&kbase[((size_t)(kt*64 + row)) * DHEAD + c4];
            KPs[row][c4+0] = kv.x; KPs[row][c4+1] = kv.y;
            KPs[row][c4+2] = kv.z; KPs[row][c4+3] = kv.w;
            float4 vv = *(const float4*)&vbase[((size_t)(kt*64 + row)) * DHEAD + c4];
            Vs[row][c4+0] = vv.x; Vs[row][c4+1] = vv.y;
            Vs[row][c4+2] = vv.z; Vs[row][c4+3] = vv.w;
        }
        __syncthreads();   // tiles visible

        // S = Q K^T (4x4 per thread)
        float s[4][4];
#pragma unroll
        for (int ri = 0; ri < 4; ++ri)
#pragma unroll
            for (int ci = 0; ci < 4; ++ci) s[ri][ci] = 0.f;
#pragma unroll
        for (int d = 0; d < 64; ++d) {
            float a_[4], b_[4];
#pragma unroll
            for (int ri = 0; ri < 4; ++ri) a_[ri] = Qs[ty*4+ri][d];
#pragma unroll
            for (int ci = 0; ci < 4; ++ci) b_[ci] = KPs[tx*4+ci][d];
#pragma unroll
            for (int ri = 0; ri < 4; ++ri)
#pragma unroll
                for (int ci = 0; ci < 4; ++ci)
                    s[ri][ci] += a_[ri] * b_[ci];
        }

        // scale + masks
#pragma unroll
        for (int ri = 0; ri < 4; ++ri) {
            int r = ty*4 + ri;
#pragma unroll
            for (int ci = 0; ci < 4; ++ci) {
                int kg = kt*64 + tx*4 + ci;
                float sv = s[ri][ci] * 0.125f
                         + attn_mask[(size_t)(qt*64 + r) * SEQ + kg];
                if (kpad[(size_t)b * SEQ + kg]) sv = -1e30f;
                s[ri][ci] = sv;
            }
        }

        // online softmax update
        float p[4][4], psum[4], mnew[4], alpha[4];
#pragma unroll
        for (int ri = 0; ri < 4; ++ri) {
            float tm = fmaxf(fmaxf(s[ri][0], s[ri][1]), fmaxf(s[ri][2], s[ri][3]));
            tm = fmaxf(tm, __shfl_xor(tm, 1, 64));
            tm = fmaxf(tm, __shfl_xor(tm, 2, 64));
            tm = fmaxf(tm, __shfl_xor(tm, 4, 64));
            tm = fmaxf(tm, __shfl_xor(tm, 8, 64));
            mnew[ri]  = fmaxf(m_i[ri], tm);
            alpha[ri] = __expf(m_i[ri] - mnew[ri]);
            float ps = 0.f;
#pragma unroll
            for (int ci = 0; ci < 4; ++ci) {
                p[ri][ci] = __expf(s[ri][ci] - mnew[ri]);
                ps += p[ri][ci];
            }
            ps += __shfl_xor(ps, 1, 64);
            ps += __shfl_xor(ps, 2, 64);
            ps += __shfl_xor(ps, 4, 64);
            ps += __shfl_xor(ps, 8, 64);
            l_i[ri] = l_i[ri] * alpha[ri] + ps;
            m_i[ri] = mnew[ri];
        }

        __syncthreads();   // all S reads of KPs done before overwrite with P^T
#pragma unroll
        for (int ri = 0; ri < 4; ++ri)
#pragma unroll
            for (int ci = 0; ci < 4; ++ci)
                KPs[tx*4+ci][ty*4+ri] = p[ri][ci];   // P^T: [key][query]
        __syncthreads();   // P^T visible

        // O = alpha*O + P V
#pragma unroll
        for (int ri = 0; ri < 4; ++ri)
#pragma unroll
            for (int ci = 0; ci < 4; ++ci) O[ri][ci] *= alpha[ri];
#pragma unroll
        for (int kk = 0; kk < 64; ++kk) {
            float a_[4], b_[4];
#pragma unroll
            for (int ri = 0; ri < 4; ++ri) a_[ri] = KPs[kk][ty*4+ri];
#pragma unroll
            for (int ci = 0; ci < 4; ++ci) b_[ci] = Vs[kk][tx*4+ci];
#pragma unroll
            for (int ri = 0; ri < 4; ++ri)
#pragma unroll
                for (int ci = 0; ci < 4; ++ci)
                    O[ri][ci] += a_[ri] * b_[ci];
        }
    }

    // write context (B,T,E) with E index = h*64 + c
#pragma unroll
    for (int ri = 0; ri < 4; ++ri) {
        int r = ty*4 + ri;
        float inv_l = 1.0f / l_i[ri];
#pragma unroll
        for (int ci = 0; ci < 4; ++ci) {
            int c = tx*4 + ci;
            ctx[((size_t)b * SEQ + qt*64 + r) * E_DIM + h*DHEAD + c] = O[ri][ci] * inv_l;
        }
    }
}

// ---------------------------------------------------------------------------
extern "C" void kernel_launch(void* const* d_in, const int* in_sizes, int n_in,
                              void* d_out, int out_size, void* d_ws, size_t ws_size,
                              hipStream_t stream)
{
    const float* query = (const float*)d_in[0];
    const float* key   = (const float*)d_in[1];
    const float* value = (const float*)d_in[2];
    const unsigned char* kpad = (const unsigned char*)d_in[3]; // all-false bools
    const float* attn_mask = (const float*)d_in[4];
    const float* w_in  = (const float*)d_in[5];   // (3072,1024)
    const float* b_in  = (const float*)d_in[6];   // (3072,)
    const float* w_out = (const float*)d_in[7];   // (1024,1024)
    const float* b_out = (const float*)d_in[8];   // (1024,)
    float* out = (float*)d_out;

    const size_t seg = (size_t)MROWS * E_DIM;     // 8M floats
    float* qws = (float*)d_ws;                    // (B,H,T,Dh)
    float* kws = qws + seg;
    float* vws = kws + seg;
    float* ctx = vws + seg;                       // (B,T,E)

    // QKV projection: grid.z selects {query,key,value} x {Wq,Wk,Wv}
    gemm_nt_kernel<<<dim3(E_DIM/128, MROWS/128, 3), 256, 0, stream>>>(
        query, key, value, w_in, b_in, qws, MROWS, E_DIM, E_DIM, 1);

    // attention: one block per (q-tile of 64, b*h)
    attn_kernel<<<dim3(SEQ/64, BATCH*NHEADS), 256, 0, stream>>>(
        qws, kws, vws, attn_mask, kpad, ctx);

    // output projection
    gemm_nt_kernel<<<dim3(E_DIM/128, MROWS/128, 1), 256, 0, stream>>>(
        ctx, ctx, ctx, w_out, b_out, out, MROWS, E_DIM, E_DIM, 0);
}

// Round 2
// 1271.003 us; speedup vs baseline: 1.5450x; 1.5450x over previous
//
#include <hip/hip_runtime.h>
#include <cstdint>
#include <cstddef>

#define E_DIM   1024
#define NHEADS  16
#define DHEAD   64
#define BATCH   8
#define SEQ     1024
#define MROWS   (BATCH*SEQ)   // 8192

typedef __bf16 bf16;
typedef __attribute__((ext_vector_type(8))) __bf16 bf16x8;
typedef __attribute__((ext_vector_type(4))) __bf16 bf16x4;
typedef __attribute__((ext_vector_type(4))) float f32x4;

typedef const __attribute__((address_space(1))) unsigned int gu32;
typedef __attribute__((address_space(3))) unsigned int lu32;

// ---------------------------------------------------------------------------
// split fp32 -> bf16 hi + bf16 lo  (hi = rn(x), lo = rn(x - hi); ~2^-17 rel)
// ---------------------------------------------------------------------------
__global__ __launch_bounds__(256)
void split_kernel(const float* __restrict__ src, bf16* __restrict__ hi,
                  bf16* __restrict__ lo, int n4)
{
    int i = blockIdx.x * 256 + threadIdx.x;
    if (i >= n4) return;
    float4 x = ((const float4*)src)[i];
    bf16x4 h, l;
    h[0] = (bf16)x.x; l[0] = (bf16)(x.x - (float)h[0]);
    h[1] = (bf16)x.y; l[1] = (bf16)(x.y - (float)h[1]);
    h[2] = (bf16)x.z; l[2] = (bf16)(x.z - (float)h[2]);
    h[3] = (bf16)x.w; l[3] = (bf16)(x.w - (float)h[3]);
    ((bf16x4*)hi)[i] = h;
    ((bf16x4*)lo)[i] = l;
}

// ---------------------------------------------------------------------------
// MFMA GEMM, split-bf16: C = A@W^T + bias computed as
//   Ahi.Whi + Ahi.Wlo + Alo.Whi  (3 phases over K)
// A: MxK (hi/lo bf16), W: NxK (hi/lo bf16). 128x128 tile, BK=32, 256 thr.
// 4 waves 2x2, each 64x64 via 4x4 grid of 16x16x32 MFMAs.
// mode 0: outF[m*N+n] = C + bias
// mode 1: split C+bias into bf16 hi/lo, scatter to (B,H,T,Dh)
// ---------------------------------------------------------------------------
__global__ __launch_bounds__(256)
void gemm_nt_mfma(const bf16* __restrict__ Ahi, const bf16* __restrict__ Alo,
                  const bf16* __restrict__ Whi, const bf16* __restrict__ Wlo,
                  const float* __restrict__ bias,
                  float* __restrict__ outF,
                  bf16* __restrict__ outHi, bf16* __restrict__ outLo,
                  int M, int N, int K, int mode)
{
    __shared__ bf16 As[128 * 32];
    __shared__ bf16 Ws[128 * 32];

    const int tid  = threadIdx.x;
    const int lane = tid & 63;
    const int wid  = tid >> 6;
    const int wm = (wid >> 1) * 64;       // wave row offset in tile
    const int wn = (wid & 1) * 64;        // wave col offset in tile
    const int fr = lane & 15;             // fragment row/col
    const int fk = (lane >> 4) * 8;       // fragment k offset

    const int mBase = blockIdx.y * 128;
    const int nBase = blockIdx.x * 128;

    // staging chunk geometry: 16B chunks; tile = 8KB = 512 chunks; 2 sets/thr
    const int rowA0 = tid >> 2;           // set 0: rows 0..63
    const int colA0 = (tid & 3) * 8;
    // set 1 chunk id = tid+256 -> row += 64, same col

    f32x4 acc[4][4];
#pragma unroll
    for (int i = 0; i < 4; ++i)
#pragma unroll
        for (int j = 0; j < 4; ++j) acc[i][j] = (f32x4){0.f, 0.f, 0.f, 0.f};

#pragma unroll 1
    for (int p = 0; p < 3; ++p) {
        const bf16* Ap = (p < 2) ? Ahi : Alo;
        const bf16* Wp = (p == 1) ? Wlo : Whi;
#pragma unroll 1
        for (int k0 = 0; k0 < K; k0 += 32) {
            // ---- stage A,W tiles via async global->LDS, width 16 ----
            const bf16* ga0 = Ap + (size_t)(mBase + rowA0) * K + k0 + colA0;
            const bf16* ga1 = ga0 + (size_t)64 * K;
            const bf16* gw0 = Wp + (size_t)(nBase + rowA0) * K + k0 + colA0;
            const bf16* gw1 = gw0 + (size_t)64 * K;
            __builtin_amdgcn_global_load_lds((gu32*)ga0, (lu32*)&As[wid * 512],        16, 0, 0);
            __builtin_amdgcn_global_load_lds((gu32*)ga1, (lu32*)&As[2048 + wid * 512], 16, 0, 0);
            __builtin_amdgcn_global_load_lds((gu32*)gw0, (lu32*)&Ws[wid * 512],        16, 0, 0);
            __builtin_amdgcn_global_load_lds((gu32*)gw1, (lu32*)&Ws[2048 + wid * 512], 16, 0, 0);
            __syncthreads();

            // ---- fragments + 16 MFMAs ----
            bf16x8 af[4], bff[4];
#pragma unroll
            for (int am = 0; am < 4; ++am)
                af[am] = *(const bf16x8*)&As[(wm + am * 16 + fr) * 32 + fk];
#pragma unroll
            for (int bn = 0; bn < 4; ++bn)
                bff[bn] = *(const bf16x8*)&Ws[(wn + bn * 16 + fr) * 32 + fk];
#pragma unroll
            for (int am = 0; am < 4; ++am)
#pragma unroll
                for (int bn = 0; bn < 4; ++bn)
                    acc[am][bn] = __builtin_amdgcn_mfma_f32_16x16x32_bf16(
                        af[am], bff[bn], acc[am][bn], 0, 0, 0);
            __syncthreads();
        }
    }

    // ---- epilogue: D row = (lane>>4)*4+reg, col = lane&15 (per 16x16 tile)
    const int drow = (lane >> 4) * 4;
    const int dcol = lane & 15;
#pragma unroll
    for (int bn = 0; bn < 4; ++bn) {
        const int col = nBase + wn + bn * 16 + dcol;
        const float bv = bias[col];
#pragma unroll
        for (int am = 0; am < 4; ++am) {
#pragma unroll
            for (int r = 0; r < 4; ++r) {
                const int row = mBase + wm + am * 16 + drow + r;
                const float v = acc[am][bn][r] + bv;
                if (mode == 0) {
                    outF[(size_t)row * N + col] = v;
                } else {
                    const int b = row >> 10, t = row & 1023;
                    const int h = col >> 6,  d = col & 63;
                    const size_t idx = (((size_t)(b * NHEADS + h)) * SEQ + t) * DHEAD + d;
                    const bf16 hv = (bf16)v;
                    outHi[idx] = hv;
                    outLo[idx] = (bf16)(v - (float)hv);
                }
            }
        }
    }
}

// ---------------------------------------------------------------------------
// Flash-style attention (fp32 math). Reads Q/K/V as bf16 hi+lo (recon fp32),
// writes ctx as bf16 hi/lo for the out-projection.
// One block = one (b,h) x 64 query rows. 256 threads as 16x16, 4x4 microtile.
// ---------------------------------------------------------------------------
__global__ __launch_bounds__(256)
void attn_kernel(const bf16* __restrict__ qkv_hi, const bf16* __restrict__ qkv_lo,
                 const float* __restrict__ attn_mask,
                 const unsigned char* __restrict__ kpad,
                 bf16* __restrict__ ctx_hi, bf16* __restrict__ ctx_lo)
{
    __shared__ float Qs [64][65];
    __shared__ float KPs[64][65];   // K tile; reused as P^T
    __shared__ float Vs [64][64];

    const int tid = threadIdx.x;
    const int tx = tid & 15, ty = tid >> 4;
    const int qt = blockIdx.x;
    const int bh = blockIdx.y;
    const int b = bh >> 4, h = bh & 15;

    const size_t seg = (size_t)MROWS * DHEAD * NHEADS / NHEADS; // 8M elems
    const size_t headoff = (size_t)bh * SEQ * DHEAD;
    const bf16* qh = qkv_hi + headoff + (size_t)qt * 64 * DHEAD;
    const bf16* ql = qkv_lo + headoff + (size_t)qt * 64 * DHEAD;
    const bf16* kh = qkv_hi + (size_t)MROWS * E_DIM     + headoff;
    const bf16* kl = qkv_lo + (size_t)MROWS * E_DIM     + headoff;
    const bf16* vh = qkv_hi + (size_t)MROWS * E_DIM * 2 + headoff;
    const bf16* vl = qkv_lo + (size_t)MROWS * E_DIM * 2 + headoff;

#pragma unroll
    for (int it = 0; it < 4; ++it) {
        int idx = tid + it * 256;
        int row = idx >> 4;
        int c4  = (idx & 15) << 2;
        bf16x4 hv = *(const bf16x4*)&qh[row * DHEAD + c4];
        bf16x4 lv = *(const bf16x4*)&ql[row * DHEAD + c4];
#pragma unroll
        for (int e = 0; e < 4; ++e) Qs[row][c4 + e] = (float)hv[e] + (float)lv[e];
    }

    float m_i[4], l_i[4], O[4][4];
#pragma unroll
    for (int ri = 0; ri < 4; ++ri) {
        m_i[ri] = -1e30f; l_i[ri] = 0.f;
#pragma unroll
        for (int ci = 0; ci < 4; ++ci) O[ri][ci] = 0.f;
    }

    for (int kt = 0; kt < 16; ++kt) {
        __syncthreads();
#pragma unroll
        for (int it = 0; it < 4; ++it) {
            int idx = tid + it * 256;
            int row = idx >> 4;
            int c4  = (idx & 15) << 2;
            bf16x4 khv = *(const bf16x4*)&kh[(kt * 64 + row) * DHEAD + c4];
            bf16x4 klv = *(const bf16x4*)&kl[(kt * 64 + row) * DHEAD + c4];
            bf16x4 vhv = *(const bf16x4*)&vh[(kt * 64 + row) * DHEAD + c4];
            bf16x4 vlv = *(const bf16x4*)&vl[(kt * 64 + row) * DHEAD + c4];
#pragma unroll
            for (int e = 0; e < 4; ++e) {
                KPs[row][c4 + e] = (float)khv[e] + (float)klv[e];
                Vs [row][c4 + e] = (float)vhv[e] + (float)vlv[e];
            }
        }
        __syncthreads();

        float s[4][4];
#pragma unroll
        for (int ri = 0; ri < 4; ++ri)
#pragma unroll
            for (int ci = 0; ci < 4; ++ci) s[ri][ci] = 0.f;
#pragma unroll
        for (int d = 0; d < 64; ++d) {
            float a_[4], b_[4];
#pragma unroll
            for (int ri = 0; ri < 4; ++ri) a_[ri] = Qs[ty*4+ri][d];
#pragma unroll
            for (int ci = 0; ci < 4; ++ci) b_[ci] = KPs[tx*4+ci][d];
#pragma unroll
            for (int ri = 0; ri < 4; ++ri)
#pragma unroll
                for (int ci = 0; ci < 4; ++ci)
                    s[ri][ci] += a_[ri] * b_[ci];
        }

#pragma unroll
        for (int ri = 0; ri < 4; ++ri) {
            int r = ty*4 + ri;
#pragma unroll
            for (int ci = 0; ci < 4; ++ci) {
                int kg = kt*64 + tx*4 + ci;
                float sv = s[ri][ci] * 0.125f
                         + attn_mask[(size_t)(qt*64 + r) * SEQ + kg];
                if (kpad[(size_t)b * SEQ + kg]) sv = -1e30f;
                s[ri][ci] = sv;
            }
        }

        float p[4][4], mnew[4], alpha[4];
#pragma unroll
        for (int ri = 0; ri < 4; ++ri) {
            float tm = fmaxf(fmaxf(s[ri][0], s[ri][1]), fmaxf(s[ri][2], s[ri][3]));
            tm = fmaxf(tm, __shfl_xor(tm, 1, 64));
            tm = fmaxf(tm, __shfl_xor(tm, 2, 64));
            tm = fmaxf(tm, __shfl_xor(tm, 4, 64));
            tm = fmaxf(tm, __shfl_xor(tm, 8, 64));
            mnew[ri]  = fmaxf(m_i[ri], tm);
            alpha[ri] = __expf(m_i[ri] - mnew[ri]);
            float ps = 0.f;
#pragma unroll
            for (int ci = 0; ci < 4; ++ci) {
                p[ri][ci] = __expf(s[ri][ci] - mnew[ri]);
                ps += p[ri][ci];
            }
            ps += __shfl_xor(ps, 1, 64);
            ps += __shfl_xor(ps, 2, 64);
            ps += __shfl_xor(ps, 4, 64);
            ps += __shfl_xor(ps, 8, 64);
            l_i[ri] = l_i[ri] * alpha[ri] + ps;
            m_i[ri] = mnew[ri];
        }

        __syncthreads();
#pragma unroll
        for (int ri = 0; ri < 4; ++ri)
#pragma unroll
            for (int ci = 0; ci < 4; ++ci)
                KPs[tx*4+ci][ty*4+ri] = p[ri][ci];
        __syncthreads();

#pragma unroll
        for (int ri = 0; ri < 4; ++ri)
#pragma unroll
            for (int ci = 0; ci < 4; ++ci) O[ri][ci] *= alpha[ri];
#pragma unroll
        for (int kk = 0; kk < 64; ++kk) {
            float a_[4], b_[4];
#pragma unroll
            for (int ri = 0; ri < 4; ++ri) a_[ri] = KPs[kk][ty*4+ri];
#pragma unroll
            for (int ci = 0; ci < 4; ++ci) b_[ci] = Vs[kk][tx*4+ci];
#pragma unroll
            for (int ri = 0; ri < 4; ++ri)
#pragma unroll
                for (int ci = 0; ci < 4; ++ci)
                    O[ri][ci] += a_[ri] * b_[ci];
        }
    }

#pragma unroll
    for (int ri = 0; ri < 4; ++ri) {
        int r = ty*4 + ri;
        float inv_l = 1.0f / l_i[ri];
#pragma unroll
        for (int ci = 0; ci < 4; ++ci) {
            int c = tx*4 + ci;
            float v = O[ri][ci] * inv_l;
            size_t idx = ((size_t)b * SEQ + qt*64 + r) * E_DIM + h*DHEAD + c;
            bf16 hv = (bf16)v;
            ctx_hi[idx] = hv;
            ctx_lo[idx] = (bf16)(v - (float)hv);
        }
    }
}

// ---------------------------------------------------------------------------
extern "C" void kernel_launch(void* const* d_in, const int* in_sizes, int n_in,
                              void* d_out, int out_size, void* d_ws, size_t ws_size,
                              hipStream_t stream)
{
    const float* inputs[3] = { (const float*)d_in[0], (const float*)d_in[1],
                               (const float*)d_in[2] };
    const unsigned char* kpad = (const unsigned char*)d_in[3];
    const float* attn_mask = (const float*)d_in[4];
    const float* w_in  = (const float*)d_in[5];
    const float* b_in  = (const float*)d_in[6];
    const float* w_out = (const float*)d_in[7];
    const float* b_out = (const float*)d_in[8];
    float* out = (float*)d_out;

    char* ws = (char*)d_ws;
    const size_t MB = 1024 * 1024;
    bf16* bufA_hi  = (bf16*)(ws + 0 * MB);    // 16MB (8M bf16), reused per z
    bf16* bufA_lo  = (bf16*)(ws + 16 * MB);   // 16MB
    bf16* w_in_hi  = (bf16*)(ws + 32 * MB);   // 6MB (3M bf16)
    bf16* w_in_lo  = (bf16*)(ws + 38 * MB);   // 6MB
    bf16* w_out_hi = (bf16*)(ws + 44 * MB);   // 2MB
    bf16* w_out_lo = (bf16*)(ws + 46 * MB);   // 2MB
    bf16* qkv_hi   = (bf16*)(ws + 48 * MB);   // 48MB (24M bf16: Q,K,V)
    bf16* qkv_lo   = (bf16*)(ws + 96 * MB);   // 48MB
    bf16* ctx_hi   = (bf16*)(ws + 0 * MB);    // 16MB (reuse bufA after QKV)
    bf16* ctx_lo   = (bf16*)(ws + 16 * MB);   // 16MB

    const size_t seg = (size_t)MROWS * E_DIM; // 8M elements

    // weights split
    split_kernel<<<(3 * E_DIM * E_DIM / 4 + 255) / 256, 256, 0, stream>>>(
        w_in, w_in_hi, w_in_lo, 3 * E_DIM * E_DIM / 4);
    split_kernel<<<(E_DIM * E_DIM / 4 + 255) / 256, 256, 0, stream>>>(
        w_out, w_out_hi, w_out_lo, E_DIM * E_DIM / 4);

    // QKV projections (per z: split input, then MFMA GEMM with scatter)
    for (int z = 0; z < 3; ++z) {
        split_kernel<<<(int)(seg / 4 / 256), 256, 0, stream>>>(
            inputs[z], bufA_hi, bufA_lo, (int)(seg / 4));
        gemm_nt_mfma<<<dim3(E_DIM / 128, MROWS / 128), 256, 0, stream>>>(
            bufA_hi, bufA_lo,
            w_in_hi + (size_t)z * E_DIM * E_DIM, w_in_lo + (size_t)z * E_DIM * E_DIM,
            b_in + z * E_DIM,
            nullptr, qkv_hi + (size_t)z * seg, qkv_lo + (size_t)z * seg,
            MROWS, E_DIM, E_DIM, 1);
    }

    // attention
    attn_kernel<<<dim3(SEQ / 64, BATCH * NHEADS), 256, 0, stream>>>(
        qkv_hi, qkv_lo, attn_mask, kpad, ctx_hi, ctx_lo);

    // output projection -> d_out (fp32)
    gemm_nt_mfma<<<dim3(E_DIM / 128, MROWS / 128), 256, 0, stream>>>(
        ctx_hi, ctx_lo, w_out_hi, w_out_lo, b_out,
        out, nullptr, nullptr, MROWS, E_DIM, E_DIM, 0);
}

// Round 3
// 678.325 us; speedup vs baseline: 2.8950x; 1.8737x over previous
//
#include <hip/hip_runtime.h>
#include <cstdint>
#include <cstddef>

#define E_DIM   1024
#define NHEADS  16
#define DHEAD   64
#define BATCH   8
#define SEQ     1024
#define MROWS   (BATCH*SEQ)   // 8192

typedef __bf16 bf16;
typedef __attribute__((ext_vector_type(8))) __bf16 bf16x8;
typedef __attribute__((ext_vector_type(4))) __bf16 bf16x4;
typedef __attribute__((ext_vector_type(4))) float f32x4;

typedef const __attribute__((address_space(1))) unsigned int gu32;
typedef __attribute__((address_space(3))) unsigned int lu32;

// ---------------------------------------------------------------------------
// split fp32 -> bf16 hi + bf16 lo
// ---------------------------------------------------------------------------
__global__ __launch_bounds__(256)
void split_kernel(const float* __restrict__ src, bf16* __restrict__ hi,
                  bf16* __restrict__ lo, int n4)
{
    int i = blockIdx.x * 256 + threadIdx.x;
    if (i >= n4) return;
    float4 x = ((const float4*)src)[i];
    bf16x4 h, l;
    h[0] = (bf16)x.x; l[0] = (bf16)(x.x - (float)h[0]);
    h[1] = (bf16)x.y; l[1] = (bf16)(x.y - (float)h[1]);
    h[2] = (bf16)x.z; l[2] = (bf16)(x.z - (float)h[2]);
    h[3] = (bf16)x.w; l[3] = (bf16)(x.w - (float)h[3]);
    ((bf16x4*)hi)[i] = h;
    ((bf16x4*)lo)[i] = l;
}

// ---------------------------------------------------------------------------
// MFMA GEMM, split-bf16: C = A@W^T + bias = Ahi.Whi + Ahi.Wlo + Alo.Whi
// mode 0: outF[m*N+n]
// mode 1: split into bf16 hi/lo, scatter to (B,H,T,Dh)
// mode 2: split into bf16 hi/lo, scatter to (B,H,Dh,T)   [transposed V]
// ---------------------------------------------------------------------------
__global__ __launch_bounds__(256)
void gemm_nt_mfma(const bf16* __restrict__ Ahi, const bf16* __restrict__ Alo,
                  const bf16* __restrict__ Whi, const bf16* __restrict__ Wlo,
                  const float* __restrict__ bias,
                  float* __restrict__ outF,
                  bf16* __restrict__ outHi, bf16* __restrict__ outLo,
                  int M, int N, int K, int mode)
{
    __shared__ bf16 As[128 * 32];
    __shared__ bf16 Ws[128 * 32];

    const int tid  = threadIdx.x;
    const int lane = tid & 63;
    const int wid  = tid >> 6;
    const int wm = (wid >> 1) * 64;
    const int wn = (wid & 1) * 64;
    const int fr = lane & 15;
    const int fk = (lane >> 4) * 8;

    const int mBase = blockIdx.y * 128;
    const int nBase = blockIdx.x * 128;

    const int rowA0 = tid >> 2;
    const int colA0 = (tid & 3) * 8;

    f32x4 acc[4][4];
#pragma unroll
    for (int i = 0; i < 4; ++i)
#pragma unroll
        for (int j = 0; j < 4; ++j) acc[i][j] = (f32x4){0.f, 0.f, 0.f, 0.f};

#pragma unroll 1
    for (int p = 0; p < 3; ++p) {
        const bf16* Ap = (p < 2) ? Ahi : Alo;
        const bf16* Wp = (p == 1) ? Wlo : Whi;
#pragma unroll 1
        for (int k0 = 0; k0 < K; k0 += 32) {
            const bf16* ga0 = Ap + (size_t)(mBase + rowA0) * K + k0 + colA0;
            const bf16* ga1 = ga0 + (size_t)64 * K;
            const bf16* gw0 = Wp + (size_t)(nBase + rowA0) * K + k0 + colA0;
            const bf16* gw1 = gw0 + (size_t)64 * K;
            __builtin_amdgcn_global_load_lds((gu32*)ga0, (lu32*)&As[wid * 512],        16, 0, 0);
            __builtin_amdgcn_global_load_lds((gu32*)ga1, (lu32*)&As[2048 + wid * 512], 16, 0, 0);
            __builtin_amdgcn_global_load_lds((gu32*)gw0, (lu32*)&Ws[wid * 512],        16, 0, 0);
            __builtin_amdgcn_global_load_lds((gu32*)gw1, (lu32*)&Ws[2048 + wid * 512], 16, 0, 0);
            __syncthreads();

            bf16x8 af[4], bff[4];
#pragma unroll
            for (int am = 0; am < 4; ++am)
                af[am] = *(const bf16x8*)&As[(wm + am * 16 + fr) * 32 + fk];
#pragma unroll
            for (int bn = 0; bn < 4; ++bn)
                bff[bn] = *(const bf16x8*)&Ws[(wn + bn * 16 + fr) * 32 + fk];
#pragma unroll
            for (int am = 0; am < 4; ++am)
#pragma unroll
                for (int bn = 0; bn < 4; ++bn)
                    acc[am][bn] = __builtin_amdgcn_mfma_f32_16x16x32_bf16(
                        af[am], bff[bn], acc[am][bn], 0, 0, 0);
            __syncthreads();
        }
    }

    const int drow = (lane >> 4) * 4;
    const int dcol = lane & 15;
#pragma unroll
    for (int bn = 0; bn < 4; ++bn) {
        const int col = nBase + wn + bn * 16 + dcol;
        const float bv = bias[col];
#pragma unroll
        for (int am = 0; am < 4; ++am) {
#pragma unroll
            for (int r = 0; r < 4; ++r) {
                const int row = mBase + wm + am * 16 + drow + r;
                const float v = acc[am][bn][r] + bv;
                if (mode == 0) {
                    outF[(size_t)row * N + col] = v;
                } else {
                    const int b = row >> 10, t = row & 1023;
                    const int h = col >> 6,  d = col & 63;
                    size_t idx;
                    if (mode == 1)
                        idx = (((size_t)(b * NHEADS + h)) * SEQ + t) * DHEAD + d;
                    else
                        idx = (((size_t)(b * NHEADS + h)) * DHEAD + d) * SEQ + t;
                    const bf16 hv = (bf16)v;
                    outHi[idx] = hv;
                    outLo[idx] = (bf16)(v - (float)hv);
                }
            }
        }
    }
}

// ---------------------------------------------------------------------------
// MFMA flash attention, split-bf16, S^T formulation.
// Block: 4 waves, 64 q rows (wave w owns q = qt*64 + w*16 + (lane&15)).
// Per kt (16 iters of 64 keys):
//   stage K (hi/lo, [key][d]) and V^T (hi/lo, [d][t]) tiles via
//   global_load_lds with XOR chunk swizzle (chunk c of row r stored at c^(r&7)).
//   S^T[key][q] = sum_d K[key][d] Q[q][d]    (A=K frag, B=Q regs, 6 MFMA/tile)
//   online softmax over keys (C-layout rows; 2 shuffles for column reduce)
//   P split hi/lo -> wave-private LDS (write b64, read back as B-frags b128)
//   O^T[d][q] += V^T P                        (A=Vt frag, B=P frag)
// ---------------------------------------------------------------------------
__global__ __launch_bounds__(256)
void attn_mfma_kernel(const bf16* __restrict__ qkv_hi, const bf16* __restrict__ qkv_lo,
                      const float* __restrict__ attn_mask,
                      const unsigned char* __restrict__ kpad,
                      bf16* __restrict__ ctx_hi, bf16* __restrict__ ctx_lo)
{
    __shared__ bf16 Khi[4096], Klo[4096], Vthi[4096], Vtlo[4096];
    __shared__ float kadd[64];
    __shared__ bf16 Pn[4][2][16 * 72];     // [wave][hi/lo][q][key(+pad)]

    const int tid  = threadIdx.x;
    const int lane = tid & 63;
    const int wid  = tid >> 6;
    const int c16  = lane & 15;            // q within wave tile / frag 16-dim
    const int quad = lane >> 4;

    const int qt = blockIdx.x;             // 0..15
    const int bh = blockIdx.y;             // 0..127
    const int b = bh >> 4, h = bh & 15;

    const size_t seg = (size_t)MROWS * E_DIM;
    const size_t headoff = (size_t)bh * SEQ * DHEAD;
    const bf16* Qhi_g  = qkv_hi + headoff;
    const bf16* Qlo_g  = qkv_lo + headoff;
    const bf16* Khi_g  = qkv_hi + seg + headoff;
    const bf16* Klo_g  = qkv_lo + seg + headoff;
    const bf16* Vthi_g = qkv_hi + 2 * seg + headoff;   // [d][t]
    const bf16* Vtlo_g = qkv_lo + 2 * seg + headoff;

    const int qloc  = wid * 16 + c16;
    const int qglob = qt * 64 + qloc;      // t index 0..1023

    // Q B-frags, resident for whole kernel
    bf16x8 qfh[2], qfl[2];
#pragma unroll
    for (int ks = 0; ks < 2; ++ks) {
        qfh[ks] = *(const bf16x8*)&Qhi_g[(size_t)qglob * DHEAD + quad * 8 + ks * 32];
        qfl[ks] = *(const bf16x8*)&Qlo_g[(size_t)qglob * DHEAD + quad * 8 + ks * 32];
    }

    float m_i = -1e30f, l_i = 0.f;
    f32x4 oacc[4];
#pragma unroll
    for (int dt = 0; dt < 4; ++dt) oacc[dt] = (f32x4){0.f, 0.f, 0.f, 0.f};

    // staging slots: thread covers chunks {tid, tid+256} of each 512-chunk tile
    const int row0 = tid >> 3,         c0 = (tid & 7) ^ (row0 & 7);
    const int row1 = (tid + 256) >> 3, c1 = ((tid + 256) & 7) ^ (row1 & 7);

#pragma unroll 1
    for (int kt = 0; kt < 16; ++kt) {
        const int ktb = kt * 64;
        __syncthreads();   // prior iter done reading K/Vt
        {
            const size_t k0 = (size_t)(ktb + row0) * DHEAD + c0 * 8;
            const size_t k1 = (size_t)(ktb + row1) * DHEAD + c1 * 8;
            const size_t v0 = (size_t)row0 * SEQ + ktb + c0 * 8;
            const size_t v1 = (size_t)row1 * SEQ + ktb + c1 * 8;
            __builtin_amdgcn_global_load_lds((gu32*)(Khi_g + k0),  (lu32*)&Khi [wid * 512],        16, 0, 0);
            __builtin_amdgcn_global_load_lds((gu32*)(Khi_g + k1),  (lu32*)&Khi [2048 + wid * 512], 16, 0, 0);
            __builtin_amdgcn_global_load_lds((gu32*)(Klo_g + k0),  (lu32*)&Klo [wid * 512],        16, 0, 0);
            __builtin_amdgcn_global_load_lds((gu32*)(Klo_g + k1),  (lu32*)&Klo [2048 + wid * 512], 16, 0, 0);
            __builtin_amdgcn_global_load_lds((gu32*)(Vthi_g + v0), (lu32*)&Vthi[wid * 512],        16, 0, 0);
            __builtin_amdgcn_global_load_lds((gu32*)(Vthi_g + v1), (lu32*)&Vthi[2048 + wid * 512], 16, 0, 0);
            __builtin_amdgcn_global_load_lds((gu32*)(Vtlo_g + v0), (lu32*)&Vtlo[wid * 512],        16, 0, 0);
            __builtin_amdgcn_global_load_lds((gu32*)(Vtlo_g + v1), (lu32*)&Vtlo[2048 + wid * 512], 16, 0, 0);
        }
        if (tid < 64) kadd[tid] = kpad[(size_t)b * SEQ + ktb + tid] ? -1e30f : 0.f;
        __syncthreads();   // tiles + kadd visible

        // mask loads (global, L2-resident), issued early
        float4 mv[4];
#pragma unroll
        for (int st = 0; st < 4; ++st)
            mv[st] = *(const float4*)&attn_mask[(size_t)qglob * SEQ + ktb + st * 16 + quad * 4];

        // ---- S^T = K.Q^T (3-term split) ----
        f32x4 sacc[4];
#pragma unroll
        for (int st = 0; st < 4; ++st) sacc[st] = (f32x4){0.f, 0.f, 0.f, 0.f};
#pragma unroll
        for (int st = 0; st < 4; ++st) {
            const int row = st * 16 + c16;      // key row in tile
            const int sw  = row & 7;
#pragma unroll
            for (int ks = 0; ks < 2; ++ks) {
                const int cp = ((quad + ks * 4) ^ sw);
                bf16x8 kh = *(const bf16x8*)&Khi[(row * 8 + cp) * 8];
                sacc[st] = __builtin_amdgcn_mfma_f32_16x16x32_bf16(kh, qfh[ks], sacc[st], 0, 0, 0);
                sacc[st] = __builtin_amdgcn_mfma_f32_16x16x32_bf16(kh, qfl[ks], sacc[st], 0, 0, 0);
                bf16x8 kl = *(const bf16x8*)&Klo[(row * 8 + cp) * 8];
                sacc[st] = __builtin_amdgcn_mfma_f32_16x16x32_bf16(kl, qfh[ks], sacc[st], 0, 0, 0);
            }
        }

        // ---- online softmax over keys (lane holds 16 keys for q=c16) ----
        float s[16];
        float tmax = -1e30f;
#pragma unroll
        for (int st = 0; st < 4; ++st) {
            float4 ka = *(const float4*)&kadd[st * 16 + quad * 4];
#pragma unroll
            for (int r = 0; r < 4; ++r) {
                float mval = (r == 0) ? mv[st].x : (r == 1) ? mv[st].y : (r == 2) ? mv[st].z : mv[st].w;
                float kav  = (r == 0) ? ka.x : (r == 1) ? ka.y : (r == 2) ? ka.z : ka.w;
                float sv = sacc[st][r] * 0.125f + mval + kav;
                s[st * 4 + r] = sv;
                tmax = fmaxf(tmax, sv);
            }
        }
        tmax = fmaxf(tmax, __shfl_xor(tmax, 16, 64));
        tmax = fmaxf(tmax, __shfl_xor(tmax, 32, 64));
        const float mnew  = fmaxf(m_i, tmax);
        const float alpha = __expf(m_i - mnew);
        float p[16], ps = 0.f;
#pragma unroll
        for (int i = 0; i < 16; ++i) { p[i] = __expf(s[i] - mnew); ps += p[i]; }
        ps += __shfl_xor(ps, 16, 64);
        ps += __shfl_xor(ps, 32, 64);
        l_i = l_i * alpha + ps;
        m_i = mnew;

        // ---- P split + wave-private LDS transform (C-layout -> B-frags) ----
#pragma unroll
        for (int st = 0; st < 4; ++st) {
            bf16x4 ph, pl;
#pragma unroll
            for (int r = 0; r < 4; ++r) {
                ph[r] = (bf16)p[st * 4 + r];
                pl[r] = (bf16)(p[st * 4 + r] - (float)ph[r]);
            }
            *(bf16x4*)&Pn[wid][0][c16 * 72 + st * 16 + quad * 4] = ph;
            *(bf16x4*)&Pn[wid][1][c16 * 72 + st * 16 + quad * 4] = pl;
        }
        bf16x8 pfh[2], pfl[2];
#pragma unroll
        for (int ks = 0; ks < 2; ++ks) {
            pfh[ks] = *(const bf16x8*)&Pn[wid][0][c16 * 72 + ks * 32 + quad * 8];
            pfl[ks] = *(const bf16x8*)&Pn[wid][1][c16 * 72 + ks * 32 + quad * 8];
        }

        // ---- O^T += V^T.P (3-term split) ----
#pragma unroll
        for (int dt = 0; dt < 4; ++dt) {
#pragma unroll
            for (int r = 0; r < 4; ++r) oacc[dt][r] *= alpha;
            const int row = dt * 16 + c16;      // d row in tile
            const int sw  = row & 7;
#pragma unroll
            for (int ks = 0; ks < 2; ++ks) {
                const int cp = ((quad + ks * 4) ^ sw);
                bf16x8 vh = *(const bf16x8*)&Vthi[(row * 8 + cp) * 8];
                oacc[dt] = __builtin_amdgcn_mfma_f32_16x16x32_bf16(vh, pfh[ks], oacc[dt], 0, 0, 0);
                oacc[dt] = __builtin_amdgcn_mfma_f32_16x16x32_bf16(vh, pfl[ks], oacc[dt], 0, 0, 0);
                bf16x8 vl = *(const bf16x8*)&Vtlo[(row * 8 + cp) * 8];
                oacc[dt] = __builtin_amdgcn_mfma_f32_16x16x32_bf16(vl, pfh[ks], oacc[dt], 0, 0, 0);
            }
        }
    }

    // ---- epilogue: O^T C-layout (d=dt*16+quad*4+r, q=c16) -> ctx (B,T,E) ----
    const float invl = 1.0f / l_i;
#pragma unroll
    for (int dt = 0; dt < 4; ++dt) {
        bf16x4 oh, ol;
#pragma unroll
        for (int r = 0; r < 4; ++r) {
            float v = oacc[dt][r] * invl;
            oh[r] = (bf16)v;
            ol[r] = (bf16)(v - (float)oh[r]);
        }
        size_t idx = ((size_t)b * SEQ + qglob) * E_DIM + h * DHEAD + dt * 16 + quad * 4;
        *(bf16x4*)&ctx_hi[idx] = oh;
        *(bf16x4*)&ctx_lo[idx] = ol;
    }
}

// ---------------------------------------------------------------------------
extern "C" void kernel_launch(void* const* d_in, const int* in_sizes, int n_in,
                              void* d_out, int out_size, void* d_ws, size_t ws_size,
                              hipStream_t stream)
{
    const float* inputs[3] = { (const float*)d_in[0], (const float*)d_in[1],
                               (const float*)d_in[2] };
    const unsigned char* kpad = (const unsigned char*)d_in[3];
    const float* attn_mask = (const float*)d_in[4];
    const float* w_in  = (const float*)d_in[5];
    const float* b_in  = (const float*)d_in[6];
    const float* w_out = (const float*)d_in[7];
    const float* b_out = (const float*)d_in[8];
    float* out = (float*)d_out;

    char* ws = (char*)d_ws;
    const size_t MB = 1024 * 1024;
    bf16* bufA_hi  = (bf16*)(ws + 0 * MB);
    bf16* bufA_lo  = (bf16*)(ws + 16 * MB);
    bf16* w_in_hi  = (bf16*)(ws + 32 * MB);
    bf16* w_in_lo  = (bf16*)(ws + 38 * MB);
    bf16* w_out_hi = (bf16*)(ws + 44 * MB);
    bf16* w_out_lo = (bf16*)(ws + 46 * MB);
    bf16* qkv_hi   = (bf16*)(ws + 48 * MB);
    bf16* qkv_lo   = (bf16*)(ws + 96 * MB);
    bf16* ctx_hi   = (bf16*)(ws + 0 * MB);    // reuse bufA after QKV
    bf16* ctx_lo   = (bf16*)(ws + 16 * MB);

    const size_t seg = (size_t)MROWS * E_DIM;

    split_kernel<<<(3 * E_DIM * E_DIM / 4 + 255) / 256, 256, 0, stream>>>(
        w_in, w_in_hi, w_in_lo, 3 * E_DIM * E_DIM / 4);
    split_kernel<<<(E_DIM * E_DIM / 4 + 255) / 256, 256, 0, stream>>>(
        w_out, w_out_hi, w_out_lo, E_DIM * E_DIM / 4);

    for (int z = 0; z < 3; ++z) {
        split_kernel<<<(int)(seg / 4 / 256), 256, 0, stream>>>(
            inputs[z], bufA_hi, bufA_lo, (int)(seg / 4));
        gemm_nt_mfma<<<dim3(E_DIM / 128, MROWS / 128), 256, 0, stream>>>(
            bufA_hi, bufA_lo,
            w_in_hi + (size_t)z * E_DIM * E_DIM, w_in_lo + (size_t)z * E_DIM * E_DIM,
            b_in + z * E_DIM,
            nullptr, qkv_hi + (size_t)z * seg, qkv_lo + (size_t)z * seg,
            MROWS, E_DIM, E_DIM, (z == 2) ? 2 : 1);
    }

    attn_mfma_kernel<<<dim3(SEQ / 64, BATCH * NHEADS), 256, 0, stream>>>(
        qkv_hi, qkv_lo, attn_mask, kpad, ctx_hi, ctx_lo);

    gemm_nt_mfma<<<dim3(E_DIM / 128, MROWS / 128), 256, 0, stream>>>(
        ctx_hi, ctx_lo, w_out_hi, w_out_lo, b_out,
        out, nullptr, nullptr, MROWS, E_DIM, E_DIM, 0);
}

// Round 4
// 638.053 us; speedup vs baseline: 3.0777x; 1.0631x over previous
//
#include <hip/hip_runtime.h>
#include <cstdint>
#include <cstddef>

#define E_DIM   1024
#define NHEADS  16
#define DHEAD   64
#define BATCH   8
#define SEQ     1024
#define MROWS   (BATCH*SEQ)   // 8192

typedef __bf16 bf16;
typedef __attribute__((ext_vector_type(8))) __bf16 bf16x8;
typedef __attribute__((ext_vector_type(4))) __bf16 bf16x4;
typedef __attribute__((ext_vector_type(4))) float f32x4;

typedef const __attribute__((address_space(1))) unsigned int gu32;
typedef __attribute__((address_space(3))) unsigned int lu32;

// ---------------------------------------------------------------------------
// split fp32 -> bf16 hi + bf16 lo
// ---------------------------------------------------------------------------
__global__ __launch_bounds__(256)
void split_kernel(const float* __restrict__ src, bf16* __restrict__ hi,
                  bf16* __restrict__ lo, int n4)
{
    int i = blockIdx.x * 256 + threadIdx.x;
    if (i >= n4) return;
    float4 x = ((const float4*)src)[i];
    bf16x4 h, l;
    h[0] = (bf16)x.x; l[0] = (bf16)(x.x - (float)h[0]);
    h[1] = (bf16)x.y; l[1] = (bf16)(x.y - (float)h[1]);
    h[2] = (bf16)x.z; l[2] = (bf16)(x.z - (float)h[2]);
    h[3] = (bf16)x.w; l[3] = (bf16)(x.w - (float)h[3]);
    ((bf16x4*)hi)[i] = h;
    ((bf16x4*)lo)[i] = l;
}

// ---------------------------------------------------------------------------
// MFMA GEMM, split-bf16, FUSED 3-term K-loop:
// per k-step stage Ahi/Alo/Whi/Wlo tiles (32KB) and run 48 MFMAs:
//   acc += Ahi.Whi + Ahi.Wlo + Alo.Whi
// mode 0: outF[m*N+n]
// mode 1: split into bf16 hi/lo, scatter to (B,H,T,Dh)
// mode 2: split into bf16 hi/lo, scatter to (B,H,Dh,T)   [transposed V]
// ---------------------------------------------------------------------------
__global__ __launch_bounds__(256)
void gemm_nt_mfma(const bf16* __restrict__ Ahi, const bf16* __restrict__ Alo,
                  const bf16* __restrict__ Whi, const bf16* __restrict__ Wlo,
                  const float* __restrict__ bias,
                  float* __restrict__ outF,
                  bf16* __restrict__ outHi, bf16* __restrict__ outLo,
                  int M, int N, int K, int mode)
{
    __shared__ bf16 Ahs[128 * 32];
    __shared__ bf16 Als[128 * 32];
    __shared__ bf16 Whs[128 * 32];
    __shared__ bf16 Wls[128 * 32];

    const int tid  = threadIdx.x;
    const int lane = tid & 63;
    const int wid  = tid >> 6;
    const int wm = (wid >> 1) * 64;
    const int wn = (wid & 1) * 64;
    const int fr = lane & 15;
    const int fk = (lane >> 4) * 8;

    const int mBase = blockIdx.y * 128;
    const int nBase = blockIdx.x * 128;

    const int rowA0 = tid >> 2;           // chunk tid   -> rows 0..63
    const int colA0 = (tid & 3) * 8;      // chunk tid+256 -> rows 64..127

    f32x4 acc[4][4];
#pragma unroll
    for (int i = 0; i < 4; ++i)
#pragma unroll
        for (int j = 0; j < 4; ++j) acc[i][j] = (f32x4){0.f, 0.f, 0.f, 0.f};

#pragma unroll 1
    for (int k0 = 0; k0 < K; k0 += 32) {
        const size_t ga0 = (size_t)(mBase + rowA0) * K + k0 + colA0;
        const size_t ga1 = ga0 + (size_t)64 * K;
        const size_t gw0 = (size_t)(nBase + rowA0) * K + k0 + colA0;
        const size_t gw1 = gw0 + (size_t)64 * K;
        __builtin_amdgcn_global_load_lds((gu32*)(Ahi + ga0), (lu32*)&Ahs[wid * 512],        16, 0, 0);
        __builtin_amdgcn_global_load_lds((gu32*)(Ahi + ga1), (lu32*)&Ahs[2048 + wid * 512], 16, 0, 0);
        __builtin_amdgcn_global_load_lds((gu32*)(Alo + ga0), (lu32*)&Als[wid * 512],        16, 0, 0);
        __builtin_amdgcn_global_load_lds((gu32*)(Alo + ga1), (lu32*)&Als[2048 + wid * 512], 16, 0, 0);
        __builtin_amdgcn_global_load_lds((gu32*)(Whi + gw0), (lu32*)&Whs[wid * 512],        16, 0, 0);
        __builtin_amdgcn_global_load_lds((gu32*)(Whi + gw1), (lu32*)&Whs[2048 + wid * 512], 16, 0, 0);
        __builtin_amdgcn_global_load_lds((gu32*)(Wlo + gw0), (lu32*)&Wls[wid * 512],        16, 0, 0);
        __builtin_amdgcn_global_load_lds((gu32*)(Wlo + gw1), (lu32*)&Wls[2048 + wid * 512], 16, 0, 0);
        __syncthreads();   // staging visible (vmcnt drained by barrier)

        bf16x8 afh[4], afl[4], bfh[4], bfl[4];
#pragma unroll
        for (int am = 0; am < 4; ++am) {
            afh[am] = *(const bf16x8*)&Ahs[(wm + am * 16 + fr) * 32 + fk];
            afl[am] = *(const bf16x8*)&Als[(wm + am * 16 + fr) * 32 + fk];
        }
#pragma unroll
        for (int bn = 0; bn < 4; ++bn) {
            bfh[bn] = *(const bf16x8*)&Whs[(wn + bn * 16 + fr) * 32 + fk];
            bfl[bn] = *(const bf16x8*)&Wls[(wn + bn * 16 + fr) * 32 + fk];
        }
#pragma unroll
        for (int am = 0; am < 4; ++am)
#pragma unroll
            for (int bn = 0; bn < 4; ++bn) {
                acc[am][bn] = __builtin_amdgcn_mfma_f32_16x16x32_bf16(afh[am], bfh[bn], acc[am][bn], 0, 0, 0);
                acc[am][bn] = __builtin_amdgcn_mfma_f32_16x16x32_bf16(afh[am], bfl[bn], acc[am][bn], 0, 0, 0);
                acc[am][bn] = __builtin_amdgcn_mfma_f32_16x16x32_bf16(afl[am], bfh[bn], acc[am][bn], 0, 0, 0);
            }
        __syncthreads();   // frag reads done before next staging
    }

    const int drow = (lane >> 4) * 4;
    const int dcol = lane & 15;
#pragma unroll
    for (int bn = 0; bn < 4; ++bn) {
        const int col = nBase + wn + bn * 16 + dcol;
        const float bv = bias[col];
#pragma unroll
        for (int am = 0; am < 4; ++am) {
#pragma unroll
            for (int r = 0; r < 4; ++r) {
                const int row = mBase + wm + am * 16 + drow + r;
                const float v = acc[am][bn][r] + bv;
                if (mode == 0) {
                    outF[(size_t)row * N + col] = v;
                } else {
                    const int b = row >> 10, t = row & 1023;
                    const int h = col >> 6,  d = col & 63;
                    size_t idx;
                    if (mode == 1)
                        idx = (((size_t)(b * NHEADS + h)) * SEQ + t) * DHEAD + d;
                    else
                        idx = (((size_t)(b * NHEADS + h)) * DHEAD + d) * SEQ + t;
                    const bf16 hv = (bf16)v;
                    outHi[idx] = hv;
                    outLo[idx] = (bf16)(v - (float)hv);
                }
            }
        }
    }
}

// ---------------------------------------------------------------------------
// MFMA flash attention, split-bf16, S^T formulation, Q-tile = 128.
// 4 waves; wave w owns 32 q rows = 2 subtiles of 16 (q = qt*128+w*32+sub*16+c16).
// Per kt (16 iters of 64 keys): stage K (hi/lo) + V^T (hi/lo) once (XOR chunk
// swizzle on the global side), then each subtile: S^T -> online softmax ->
// P hi/lo via wave-private LDS -> O^T += V^T.P.  kpad additions preloaded.
// ---------------------------------------------------------------------------
__global__ __launch_bounds__(256)
void attn_mfma_kernel(const bf16* __restrict__ qkv_hi, const bf16* __restrict__ qkv_lo,
                      const float* __restrict__ attn_mask,
                      const unsigned char* __restrict__ kpad,
                      bf16* __restrict__ ctx_hi, bf16* __restrict__ ctx_lo)
{
    __shared__ bf16 Khi[4096], Klo[4096], Vthi[4096], Vtlo[4096];  // 32 KB
    __shared__ float kaddf[1024];                                   // 4 KB
    __shared__ bf16 Pn[4][2][16 * 72];                              // 18 KB

    const int tid  = threadIdx.x;
    const int lane = tid & 63;
    const int wid  = tid >> 6;
    const int c16  = lane & 15;
    const int quad = lane >> 4;

    const int qt = blockIdx.x;             // 0..7
    const int bh = blockIdx.y;             // 0..127
    const int b = bh >> 4, h = bh & 15;

    const size_t seg = (size_t)MROWS * E_DIM;
    const size_t headoff = (size_t)bh * SEQ * DHEAD;
    const bf16* Qhi_g  = qkv_hi + headoff;
    const bf16* Qlo_g  = qkv_lo + headoff;
    const bf16* Khi_g  = qkv_hi + seg + headoff;
    const bf16* Klo_g  = qkv_lo + seg + headoff;
    const bf16* Vthi_g = qkv_hi + 2 * seg + headoff;   // [d][t]
    const bf16* Vtlo_g = qkv_lo + 2 * seg + headoff;

    int qglob[2];
    qglob[0] = qt * 128 + wid * 32 + c16;
    qglob[1] = qglob[0] + 16;

    // Q B-frags for both subtiles, resident for whole kernel
    bf16x8 qfh[2][2], qfl[2][2];
#pragma unroll
    for (int sub = 0; sub < 2; ++sub)
#pragma unroll
        for (int ks = 0; ks < 2; ++ks) {
            qfh[sub][ks] = *(const bf16x8*)&Qhi_g[(size_t)qglob[sub] * DHEAD + quad * 8 + ks * 32];
            qfl[sub][ks] = *(const bf16x8*)&Qlo_g[(size_t)qglob[sub] * DHEAD + quad * 8 + ks * 32];
        }

    // preload key-padding additions
    for (int i = tid; i < SEQ; i += 256)
        kaddf[i] = kpad[(size_t)b * SEQ + i] ? -1e30f : 0.f;

    float m_i[2] = {-1e30f, -1e30f}, l_i[2] = {0.f, 0.f};
    f32x4 oacc[2][4];
#pragma unroll
    for (int sub = 0; sub < 2; ++sub)
#pragma unroll
        for (int dt = 0; dt < 4; ++dt) oacc[sub][dt] = (f32x4){0.f, 0.f, 0.f, 0.f};

    const int row0 = tid >> 3,         c0 = (tid & 7) ^ (row0 & 7);
    const int row1 = (tid + 256) >> 3, c1 = ((tid + 256) & 7) ^ (row1 & 7);

#pragma unroll 1
    for (int kt = 0; kt < 16; ++kt) {
        const int ktb = kt * 64;
        __syncthreads();   // prior iter done reading K/Vt (and kaddf written, iter 0)
        {
            const size_t k0 = (size_t)(ktb + row0) * DHEAD + c0 * 8;
            const size_t k1 = (size_t)(ktb + row1) * DHEAD + c1 * 8;
            const size_t v0 = (size_t)row0 * SEQ + ktb + c0 * 8;
            const size_t v1 = (size_t)row1 * SEQ + ktb + c1 * 8;
            __builtin_amdgcn_global_load_lds((gu32*)(Khi_g + k0),  (lu32*)&Khi [wid * 512],        16, 0, 0);
            __builtin_amdgcn_global_load_lds((gu32*)(Khi_g + k1),  (lu32*)&Khi [2048 + wid * 512], 16, 0, 0);
            __builtin_amdgcn_global_load_lds((gu32*)(Klo_g + k0),  (lu32*)&Klo [wid * 512],        16, 0, 0);
            __builtin_amdgcn_global_load_lds((gu32*)(Klo_g + k1),  (lu32*)&Klo [2048 + wid * 512], 16, 0, 0);
            __builtin_amdgcn_global_load_lds((gu32*)(Vthi_g + v0), (lu32*)&Vthi[wid * 512],        16, 0, 0);
            __builtin_amdgcn_global_load_lds((gu32*)(Vthi_g + v1), (lu32*)&Vthi[2048 + wid * 512], 16, 0, 0);
            __builtin_amdgcn_global_load_lds((gu32*)(Vtlo_g + v0), (lu32*)&Vtlo[wid * 512],        16, 0, 0);
            __builtin_amdgcn_global_load_lds((gu32*)(Vtlo_g + v1), (lu32*)&Vtlo[2048 + wid * 512], 16, 0, 0);
        }

        // mask loads for both subtiles, issued before the barrier wait
        float4 mv[2][4];
#pragma unroll
        for (int sub = 0; sub < 2; ++sub)
#pragma unroll
            for (int st = 0; st < 4; ++st)
                mv[sub][st] = *(const float4*)&attn_mask[(size_t)qglob[sub] * SEQ + ktb + st * 16 + quad * 4];

        __syncthreads();   // tiles visible

#pragma unroll
        for (int sub = 0; sub < 2; ++sub) {
            // ---- S^T = K.Q^T (3-term split) ----
            f32x4 sacc[4];
#pragma unroll
            for (int st = 0; st < 4; ++st) sacc[st] = (f32x4){0.f, 0.f, 0.f, 0.f};
#pragma unroll
            for (int st = 0; st < 4; ++st) {
                const int row = st * 16 + c16;
                const int sw  = row & 7;
#pragma unroll
                for (int ks = 0; ks < 2; ++ks) {
                    const int cp = ((quad + ks * 4) ^ sw);
                    bf16x8 kh = *(const bf16x8*)&Khi[(row * 8 + cp) * 8];
                    sacc[st] = __builtin_amdgcn_mfma_f32_16x16x32_bf16(kh, qfh[sub][ks], sacc[st], 0, 0, 0);
                    sacc[st] = __builtin_amdgcn_mfma_f32_16x16x32_bf16(kh, qfl[sub][ks], sacc[st], 0, 0, 0);
                    bf16x8 kl = *(const bf16x8*)&Klo[(row * 8 + cp) * 8];
                    sacc[st] = __builtin_amdgcn_mfma_f32_16x16x32_bf16(kl, qfh[sub][ks], sacc[st], 0, 0, 0);
                }
            }

            // ---- online softmax over keys ----
            float s[16], tmax = -1e30f;
#pragma unroll
            for (int st = 0; st < 4; ++st) {
                float4 ka = *(const float4*)&kaddf[ktb + st * 16 + quad * 4];
#pragma unroll
                for (int r = 0; r < 4; ++r) {
                    float mval = (r == 0) ? mv[sub][st].x : (r == 1) ? mv[sub][st].y
                               : (r == 2) ? mv[sub][st].z : mv[sub][st].w;
                    float kav  = (r == 0) ? ka.x : (r == 1) ? ka.y : (r == 2) ? ka.z : ka.w;
                    float sv = sacc[st][r] * 0.125f + mval + kav;
                    s[st * 4 + r] = sv;
                    tmax = fmaxf(tmax, sv);
                }
            }
            tmax = fmaxf(tmax, __shfl_xor(tmax, 16, 64));
            tmax = fmaxf(tmax, __shfl_xor(tmax, 32, 64));
            const float mnew  = fmaxf(m_i[sub], tmax);
            const float alpha = __expf(m_i[sub] - mnew);
            float p[16], ps = 0.f;
#pragma unroll
            for (int i = 0; i < 16; ++i) { p[i] = __expf(s[i] - mnew); ps += p[i]; }
            ps += __shfl_xor(ps, 16, 64);
            ps += __shfl_xor(ps, 32, 64);
            l_i[sub] = l_i[sub] * alpha + ps;
            m_i[sub] = mnew;

            // ---- P split + wave-private LDS transform ----
#pragma unroll
            for (int st = 0; st < 4; ++st) {
                bf16x4 ph, pl;
#pragma unroll
                for (int r = 0; r < 4; ++r) {
                    ph[r] = (bf16)p[st * 4 + r];
                    pl[r] = (bf16)(p[st * 4 + r] - (float)ph[r]);
                }
                *(bf16x4*)&Pn[wid][0][c16 * 72 + st * 16 + quad * 4] = ph;
                *(bf16x4*)&Pn[wid][1][c16 * 72 + st * 16 + quad * 4] = pl;
            }
            bf16x8 pfh[2], pfl[2];
#pragma unroll
            for (int ks = 0; ks < 2; ++ks) {
                pfh[ks] = *(const bf16x8*)&Pn[wid][0][c16 * 72 + ks * 32 + quad * 8];
                pfl[ks] = *(const bf16x8*)&Pn[wid][1][c16 * 72 + ks * 32 + quad * 8];
            }

            // ---- O^T += V^T.P (3-term split) ----
#pragma unroll
            for (int dt = 0; dt < 4; ++dt) {
#pragma unroll
                for (int r = 0; r < 4; ++r) oacc[sub][dt][r] *= alpha;
                const int row = dt * 16 + c16;
                const int sw  = row & 7;
#pragma unroll
                for (int ks = 0; ks < 2; ++ks) {
                    const int cp = ((quad + ks * 4) ^ sw);
                    bf16x8 vh = *(const bf16x8*)&Vthi[(row * 8 + cp) * 8];
                    oacc[sub][dt] = __builtin_amdgcn_mfma_f32_16x16x32_bf16(vh, pfh[ks], oacc[sub][dt], 0, 0, 0);
                    oacc[sub][dt] = __builtin_amdgcn_mfma_f32_16x16x32_bf16(vh, pfl[ks], oacc[sub][dt], 0, 0, 0);
                    bf16x8 vl = *(const bf16x8*)&Vtlo[(row * 8 + cp) * 8];
                    oacc[sub][dt] = __builtin_amdgcn_mfma_f32_16x16x32_bf16(vl, pfh[ks], oacc[sub][dt], 0, 0, 0);
                }
            }
        }
    }

    // ---- epilogue ----
#pragma unroll
    for (int sub = 0; sub < 2; ++sub) {
        const float invl = 1.0f / l_i[sub];
#pragma unroll
        for (int dt = 0; dt < 4; ++dt) {
            bf16x4 oh, ol;
#pragma unroll
            for (int r = 0; r < 4; ++r) {
                float v = oacc[sub][dt][r] * invl;
                oh[r] = (bf16)v;
                ol[r] = (bf16)(v - (float)oh[r]);
            }
            size_t idx = ((size_t)b * SEQ + qglob[sub]) * E_DIM + h * DHEAD + dt * 16 + quad * 4;
            *(bf16x4*)&ctx_hi[idx] = oh;
            *(bf16x4*)&ctx_lo[idx] = ol;
        }
    }
}

// ---------------------------------------------------------------------------
extern "C" void kernel_launch(void* const* d_in, const int* in_sizes, int n_in,
                              void* d_out, int out_size, void* d_ws, size_t ws_size,
                              hipStream_t stream)
{
    const float* inputs[3] = { (const float*)d_in[0], (const float*)d_in[1],
                               (const float*)d_in[2] };
    const unsigned char* kpad = (const unsigned char*)d_in[3];
    const float* attn_mask = (const float*)d_in[4];
    const float* w_in  = (const float*)d_in[5];
    const float* b_in  = (const float*)d_in[6];
    const float* w_out = (const float*)d_in[7];
    const float* b_out = (const float*)d_in[8];
    float* out = (float*)d_out;

    char* ws = (char*)d_ws;
    const size_t MB = 1024 * 1024;
    bf16* bufA_hi  = (bf16*)(ws + 0 * MB);
    bf16* bufA_lo  = (bf16*)(ws + 16 * MB);
    bf16* w_in_hi  = (bf16*)(ws + 32 * MB);
    bf16* w_in_lo  = (bf16*)(ws + 38 * MB);
    bf16* w_out_hi = (bf16*)(ws + 44 * MB);
    bf16* w_out_lo = (bf16*)(ws + 46 * MB);
    bf16* qkv_hi   = (bf16*)(ws + 48 * MB);
    bf16* qkv_lo   = (bf16*)(ws + 96 * MB);
    bf16* ctx_hi   = (bf16*)(ws + 0 * MB);    // reuse bufA after QKV
    bf16* ctx_lo   = (bf16*)(ws + 16 * MB);

    const size_t seg = (size_t)MROWS * E_DIM;

    split_kernel<<<(3 * E_DIM * E_DIM / 4 + 255) / 256, 256, 0, stream>>>(
        w_in, w_in_hi, w_in_lo, 3 * E_DIM * E_DIM / 4);
    split_kernel<<<(E_DIM * E_DIM / 4 + 255) / 256, 256, 0, stream>>>(
        w_out, w_out_hi, w_out_lo, E_DIM * E_DIM / 4);

    for (int z = 0; z < 3; ++z) {
        split_kernel<<<(int)(seg / 4 / 256), 256, 0, stream>>>(
            inputs[z], bufA_hi, bufA_lo, (int)(seg / 4));
        gemm_nt_mfma<<<dim3(E_DIM / 128, MROWS / 128), 256, 0, stream>>>(
            bufA_hi, bufA_lo,
            w_in_hi + (size_t)z * E_DIM * E_DIM, w_in_lo + (size_t)z * E_DIM * E_DIM,
            b_in + z * E_DIM,
            nullptr, qkv_hi + (size_t)z * seg, qkv_lo + (size_t)z * seg,
            MROWS, E_DIM, E_DIM, (z == 2) ? 2 : 1);
    }

    attn_mfma_kernel<<<dim3(SEQ / 128, BATCH * NHEADS), 256, 0, stream>>>(
        qkv_hi, qkv_lo, attn_mask, kpad, ctx_hi, ctx_lo);

    gemm_nt_mfma<<<dim3(E_DIM / 128, MROWS / 128), 256, 0, stream>>>(
        ctx_hi, ctx_lo, w_out_hi, w_out_lo, b_out,
        out, nullptr, nullptr, MROWS, E_DIM, E_DIM, 0);
}

// Round 5
// 612.999 us; speedup vs baseline: 3.2035x; 1.0409x over previous
//
#include <hip/hip_runtime.h>
#include <cstdint>
#include <cstddef>

#define E_DIM   1024
#define NHEADS  16
#define DHEAD   64
#define BATCH   8
#define SEQ     1024
#define MROWS   (BATCH*SEQ)   // 8192

typedef __bf16 bf16;
typedef __attribute__((ext_vector_type(8))) __bf16 bf16x8;
typedef __attribute__((ext_vector_type(4))) __bf16 bf16x4;
typedef __attribute__((ext_vector_type(4))) float f32x4;

typedef const __attribute__((address_space(1))) unsigned int gu32;
typedef __attribute__((address_space(3))) unsigned int lu32;

// ---------------------------------------------------------------------------
// split fp32 -> bf16 hi + bf16 lo
// ---------------------------------------------------------------------------
__global__ __launch_bounds__(256)
void split_kernel(const float* __restrict__ src, bf16* __restrict__ hi,
                  bf16* __restrict__ lo, int n4)
{
    int i = blockIdx.x * 256 + threadIdx.x;
    if (i >= n4) return;
    float4 x = ((const float4*)src)[i];
    bf16x4 h, l;
    h[0] = (bf16)x.x; l[0] = (bf16)(x.x - (float)h[0]);
    h[1] = (bf16)x.y; l[1] = (bf16)(x.y - (float)h[1]);
    h[2] = (bf16)x.z; l[2] = (bf16)(x.z - (float)h[2]);
    h[3] = (bf16)x.w; l[3] = (bf16)(x.w - (float)h[3]);
    ((bf16x4*)hi)[i] = h;
    ((bf16x4*)lo)[i] = l;
}

// fp32 -> bf16 (mask)
__global__ __launch_bounds__(256)
void cvt_bf16_kernel(const float* __restrict__ src, bf16* __restrict__ dst, int n4)
{
    int i = blockIdx.x * 256 + threadIdx.x;
    if (i >= n4) return;
    float4 x = ((const float4*)src)[i];
    bf16x4 h;
    h[0] = (bf16)x.x; h[1] = (bf16)x.y; h[2] = (bf16)x.z; h[3] = (bf16)x.w;
    ((bf16x4*)dst)[i] = h;
}

// ---------------------------------------------------------------------------
// MFMA GEMM, split-bf16, fused 3-term K-loop (48 MFMAs / k-step):
//   acc += Ahi.Whi + Ahi.Wlo + Alo.Whi
// mode 0: outF[m*N+n]  (fp32)
// mode 1: bf16 (hi only) scatter to (B,H,T,Dh)
// mode 2: bf16 (hi only) scatter to (B,H,Dh,T)   [transposed V]
// ---------------------------------------------------------------------------
__global__ __launch_bounds__(256)
void gemm_nt_mfma(const bf16* __restrict__ Ahi, const bf16* __restrict__ Alo,
                  const bf16* __restrict__ Whi, const bf16* __restrict__ Wlo,
                  const float* __restrict__ bias,
                  float* __restrict__ outF, bf16* __restrict__ outHi,
                  int M, int N, int K, int mode)
{
    __shared__ bf16 Ahs[128 * 32];
    __shared__ bf16 Als[128 * 32];
    __shared__ bf16 Whs[128 * 32];
    __shared__ bf16 Wls[128 * 32];

    const int tid  = threadIdx.x;
    const int lane = tid & 63;
    const int wid  = tid >> 6;
    const int wm = (wid >> 1) * 64;
    const int wn = (wid & 1) * 64;
    const int fr = lane & 15;
    const int fk = (lane >> 4) * 8;

    const int mBase = blockIdx.y * 128;
    const int nBase = blockIdx.x * 128;

    const int rowA0 = tid >> 2;
    const int colA0 = (tid & 3) * 8;

    f32x4 acc[4][4];
#pragma unroll
    for (int i = 0; i < 4; ++i)
#pragma unroll
        for (int j = 0; j < 4; ++j) acc[i][j] = (f32x4){0.f, 0.f, 0.f, 0.f};

#pragma unroll 1
    for (int k0 = 0; k0 < K; k0 += 32) {
        const size_t ga0 = (size_t)(mBase + rowA0) * K + k0 + colA0;
        const size_t ga1 = ga0 + (size_t)64 * K;
        const size_t gw0 = (size_t)(nBase + rowA0) * K + k0 + colA0;
        const size_t gw1 = gw0 + (size_t)64 * K;
        __builtin_amdgcn_global_load_lds((gu32*)(Ahi + ga0), (lu32*)&Ahs[wid * 512],        16, 0, 0);
        __builtin_amdgcn_global_load_lds((gu32*)(Ahi + ga1), (lu32*)&Ahs[2048 + wid * 512], 16, 0, 0);
        __builtin_amdgcn_global_load_lds((gu32*)(Alo + ga0), (lu32*)&Als[wid * 512],        16, 0, 0);
        __builtin_amdgcn_global_load_lds((gu32*)(Alo + ga1), (lu32*)&Als[2048 + wid * 512], 16, 0, 0);
        __builtin_amdgcn_global_load_lds((gu32*)(Whi + gw0), (lu32*)&Whs[wid * 512],        16, 0, 0);
        __builtin_amdgcn_global_load_lds((gu32*)(Whi + gw1), (lu32*)&Whs[2048 + wid * 512], 16, 0, 0);
        __builtin_amdgcn_global_load_lds((gu32*)(Wlo + gw0), (lu32*)&Wls[wid * 512],        16, 0, 0);
        __builtin_amdgcn_global_load_lds((gu32*)(Wlo + gw1), (lu32*)&Wls[2048 + wid * 512], 16, 0, 0);
        __syncthreads();

        bf16x8 afh[4], afl[4], bfh[4], bfl[4];
#pragma unroll
        for (int am = 0; am < 4; ++am) {
            afh[am] = *(const bf16x8*)&Ahs[(wm + am * 16 + fr) * 32 + fk];
            afl[am] = *(const bf16x8*)&Als[(wm + am * 16 + fr) * 32 + fk];
        }
#pragma unroll
        for (int bn = 0; bn < 4; ++bn) {
            bfh[bn] = *(const bf16x8*)&Whs[(wn + bn * 16 + fr) * 32 + fk];
            bfl[bn] = *(const bf16x8*)&Wls[(wn + bn * 16 + fr) * 32 + fk];
        }
#pragma unroll
        for (int am = 0; am < 4; ++am)
#pragma unroll
            for (int bn = 0; bn < 4; ++bn) {
                acc[am][bn] = __builtin_amdgcn_mfma_f32_16x16x32_bf16(afh[am], bfh[bn], acc[am][bn], 0, 0, 0);
                acc[am][bn] = __builtin_amdgcn_mfma_f32_16x16x32_bf16(afh[am], bfl[bn], acc[am][bn], 0, 0, 0);
                acc[am][bn] = __builtin_amdgcn_mfma_f32_16x16x32_bf16(afl[am], bfh[bn], acc[am][bn], 0, 0, 0);
            }
        __syncthreads();
    }

    const int drow = (lane >> 4) * 4;
    const int dcol = lane & 15;
#pragma unroll
    for (int bn = 0; bn < 4; ++bn) {
        const int col = nBase + wn + bn * 16 + dcol;
        const float bv = bias[col];
#pragma unroll
        for (int am = 0; am < 4; ++am) {
#pragma unroll
            for (int r = 0; r < 4; ++r) {
                const int row = mBase + wm + am * 16 + drow + r;
                const float v = acc[am][bn][r] + bv;
                if (mode == 0) {
                    outF[(size_t)row * N + col] = v;
                } else {
                    const int b = row >> 10, t = row & 1023;
                    const int h = col >> 6,  d = col & 63;
                    size_t idx;
                    if (mode == 1)
                        idx = (((size_t)(b * NHEADS + h)) * SEQ + t) * DHEAD + d;
                    else
                        idx = (((size_t)(b * NHEADS + h)) * DHEAD + d) * SEQ + t;
                    outHi[idx] = (bf16)v;
                }
            }
        }
    }
}

// ---------------------------------------------------------------------------
// MFMA flash attention, single-bf16, S^T formulation, Q-tile = 128.
// 4 waves; wave w owns 32 q rows = 2 subtiles of 16.
// Per kt (16 iters of 64 keys): stage K + V^T once (XOR chunk swizzle on the
// global side), then per subtile: S^T (2 MFMA x 4) -> online softmax ->
// P bf16 via wave-private LDS -> O^T += V^T.P (2 MFMA x 4).
// attn_mask pre-converted to bf16; kpad additions preloaded to LDS.
// ---------------------------------------------------------------------------
__global__ __launch_bounds__(256)
void attn_mfma_kernel(const bf16* __restrict__ qkv,
                      const bf16* __restrict__ mask_bf,
                      const unsigned char* __restrict__ kpad,
                      bf16* __restrict__ ctx_hi, bf16* __restrict__ ctx_lo)
{
    __shared__ bf16 Khi[4096], Vthi[4096];      // 16 KB
    __shared__ float kaddf[1024];               // 4 KB
    __shared__ bf16 Pn[4][16 * 72];             // 9 KB

    const int tid  = threadIdx.x;
    const int lane = tid & 63;
    const int wid  = tid >> 6;
    const int c16  = lane & 15;
    const int quad = lane >> 4;

    const int qt = blockIdx.x;             // 0..7
    const int bh = blockIdx.y;             // 0..127
    const int b = bh >> 4, h = bh & 15;

    const size_t seg = (size_t)MROWS * E_DIM;
    const size_t headoff = (size_t)bh * SEQ * DHEAD;
    const bf16* Q_g  = qkv + headoff;
    const bf16* K_g  = qkv + seg + headoff;
    const bf16* Vt_g = qkv + 2 * seg + headoff;   // [d][t]

    int qglob[2];
    qglob[0] = qt * 128 + wid * 32 + c16;
    qglob[1] = qglob[0] + 16;

    // Q B-frags for both subtiles, resident for whole kernel
    bf16x8 qf[2][2];
#pragma unroll
    for (int sub = 0; sub < 2; ++sub)
#pragma unroll
        for (int ks = 0; ks < 2; ++ks)
            qf[sub][ks] = *(const bf16x8*)&Q_g[(size_t)qglob[sub] * DHEAD + quad * 8 + ks * 32];

    for (int i = tid; i < SEQ; i += 256)
        kaddf[i] = kpad[(size_t)b * SEQ + i] ? -1e30f : 0.f;

    float m_i[2] = {-1e30f, -1e30f}, l_i[2] = {0.f, 0.f};
    f32x4 oacc[2][4];
#pragma unroll
    for (int sub = 0; sub < 2; ++sub)
#pragma unroll
        for (int dt = 0; dt < 4; ++dt) oacc[sub][dt] = (f32x4){0.f, 0.f, 0.f, 0.f};

    const int row0 = tid >> 3,         c0 = (tid & 7) ^ (row0 & 7);
    const int row1 = (tid + 256) >> 3, c1 = ((tid + 256) & 7) ^ (row1 & 7);

#pragma unroll 1
    for (int kt = 0; kt < 16; ++kt) {
        const int ktb = kt * 64;
        __syncthreads();   // prior iter done reading K/Vt (kaddf ready, iter 0)
        {
            const size_t k0 = (size_t)(ktb + row0) * DHEAD + c0 * 8;
            const size_t k1 = (size_t)(ktb + row1) * DHEAD + c1 * 8;
            const size_t v0 = (size_t)row0 * SEQ + ktb + c0 * 8;
            const size_t v1 = (size_t)row1 * SEQ + ktb + c1 * 8;
            __builtin_amdgcn_global_load_lds((gu32*)(K_g + k0),  (lu32*)&Khi [wid * 512],        16, 0, 0);
            __builtin_amdgcn_global_load_lds((gu32*)(K_g + k1),  (lu32*)&Khi [2048 + wid * 512], 16, 0, 0);
            __builtin_amdgcn_global_load_lds((gu32*)(Vt_g + v0), (lu32*)&Vthi[wid * 512],        16, 0, 0);
            __builtin_amdgcn_global_load_lds((gu32*)(Vt_g + v1), (lu32*)&Vthi[2048 + wid * 512], 16, 0, 0);
        }

        // mask loads (bf16), issued before the barrier wait
        bf16x4 mvh[2][4];
#pragma unroll
        for (int sub = 0; sub < 2; ++sub)
#pragma unroll
            for (int st = 0; st < 4; ++st)
                mvh[sub][st] = *(const bf16x4*)&mask_bf[(size_t)qglob[sub] * SEQ + ktb + st * 16 + quad * 4];

        __syncthreads();   // tiles visible

#pragma unroll
        for (int sub = 0; sub < 2; ++sub) {
            // ---- S^T = K.Q^T ----
            f32x4 sacc[4];
#pragma unroll
            for (int st = 0; st < 4; ++st) sacc[st] = (f32x4){0.f, 0.f, 0.f, 0.f};
#pragma unroll
            for (int st = 0; st < 4; ++st) {
                const int row = st * 16 + c16;
                const int sw  = row & 7;
#pragma unroll
                for (int ks = 0; ks < 2; ++ks) {
                    const int cp = ((quad + ks * 4) ^ sw);
                    bf16x8 kh = *(const bf16x8*)&Khi[(row * 8 + cp) * 8];
                    sacc[st] = __builtin_amdgcn_mfma_f32_16x16x32_bf16(kh, qf[sub][ks], sacc[st], 0, 0, 0);
                }
            }

            // ---- online softmax over keys ----
            float s[16], tmax = -1e30f;
#pragma unroll
            for (int st = 0; st < 4; ++st) {
                float4 ka = *(const float4*)&kaddf[ktb + st * 16 + quad * 4];
#pragma unroll
                for (int r = 0; r < 4; ++r) {
                    float kav = (r == 0) ? ka.x : (r == 1) ? ka.y : (r == 2) ? ka.z : ka.w;
                    float sv = sacc[st][r] * 0.125f + (float)mvh[sub][st][r] + kav;
                    s[st * 4 + r] = sv;
                    tmax = fmaxf(tmax, sv);
                }
            }
            tmax = fmaxf(tmax, __shfl_xor(tmax, 16, 64));
            tmax = fmaxf(tmax, __shfl_xor(tmax, 32, 64));
            const float mnew  = fmaxf(m_i[sub], tmax);
            const float alpha = __expf(m_i[sub] - mnew);
            float p[16], ps = 0.f;
#pragma unroll
            for (int i = 0; i < 16; ++i) { p[i] = __expf(s[i] - mnew); ps += p[i]; }
            ps += __shfl_xor(ps, 16, 64);
            ps += __shfl_xor(ps, 32, 64);
            l_i[sub] = l_i[sub] * alpha + ps;
            m_i[sub] = mnew;

            // ---- P (bf16) via wave-private LDS transform ----
#pragma unroll
            for (int st = 0; st < 4; ++st) {
                bf16x4 ph;
#pragma unroll
                for (int r = 0; r < 4; ++r) ph[r] = (bf16)p[st * 4 + r];
                *(bf16x4*)&Pn[wid][c16 * 72 + st * 16 + quad * 4] = ph;
            }
            bf16x8 pf[2];
#pragma unroll
            for (int ks = 0; ks < 2; ++ks)
                pf[ks] = *(const bf16x8*)&Pn[wid][c16 * 72 + ks * 32 + quad * 8];

            // ---- O^T += V^T.P ----
#pragma unroll
            for (int dt = 0; dt < 4; ++dt) {
#pragma unroll
                for (int r = 0; r < 4; ++r) oacc[sub][dt][r] *= alpha;
                const int row = dt * 16 + c16;
                const int sw  = row & 7;
#pragma unroll
                for (int ks = 0; ks < 2; ++ks) {
                    const int cp = ((quad + ks * 4) ^ sw);
                    bf16x8 vh = *(const bf16x8*)&Vthi[(row * 8 + cp) * 8];
                    oacc[sub][dt] = __builtin_amdgcn_mfma_f32_16x16x32_bf16(vh, pf[ks], oacc[sub][dt], 0, 0, 0);
                }
            }
        }
    }

    // ---- epilogue: split O into hi/lo for the out-projection ----
#pragma unroll
    for (int sub = 0; sub < 2; ++sub) {
        const float invl = 1.0f / l_i[sub];
#pragma unroll
        for (int dt = 0; dt < 4; ++dt) {
            bf16x4 oh, ol;
#pragma unroll
            for (int r = 0; r < 4; ++r) {
                float v = oacc[sub][dt][r] * invl;
                oh[r] = (bf16)v;
                ol[r] = (bf16)(v - (float)oh[r]);
            }
            size_t idx = ((size_t)b * SEQ + qglob[sub]) * E_DIM + h * DHEAD + dt * 16 + quad * 4;
            *(bf16x4*)&ctx_hi[idx] = oh;
            *(bf16x4*)&ctx_lo[idx] = ol;
        }
    }
}

// ---------------------------------------------------------------------------
extern "C" void kernel_launch(void* const* d_in, const int* in_sizes, int n_in,
                              void* d_out, int out_size, void* d_ws, size_t ws_size,
                              hipStream_t stream)
{
    const float* inputs[3] = { (const float*)d_in[0], (const float*)d_in[1],
                               (const float*)d_in[2] };
    const unsigned char* kpad = (const unsigned char*)d_in[3];
    const float* attn_mask = (const float*)d_in[4];
    const float* w_in  = (const float*)d_in[5];
    const float* b_in  = (const float*)d_in[6];
    const float* w_out = (const float*)d_in[7];
    const float* b_out = (const float*)d_in[8];
    float* out = (float*)d_out;

    char* ws = (char*)d_ws;
    const size_t MB = 1024 * 1024;
    bf16* bufA_hi  = (bf16*)(ws + 0 * MB);    // 16MB per-z reuse
    bf16* bufA_lo  = (bf16*)(ws + 16 * MB);   // 16MB
    bf16* w_in_hi  = (bf16*)(ws + 32 * MB);   // 6MB
    bf16* w_in_lo  = (bf16*)(ws + 38 * MB);   // 6MB
    bf16* w_out_hi = (bf16*)(ws + 44 * MB);   // 2MB
    bf16* w_out_lo = (bf16*)(ws + 46 * MB);   // 2MB
    bf16* qkv      = (bf16*)(ws + 48 * MB);   // 48MB (Q,K,Vt bf16)
    bf16* mask_bf  = (bf16*)(ws + 96 * MB);   // 2MB
    bf16* ctx_hi   = (bf16*)(ws + 0 * MB);    // reuse bufA after QKV
    bf16* ctx_lo   = (bf16*)(ws + 16 * MB);

    const size_t seg = (size_t)MROWS * E_DIM;

    split_kernel<<<(3 * E_DIM * E_DIM / 4 + 255) / 256, 256, 0, stream>>>(
        w_in, w_in_hi, w_in_lo, 3 * E_DIM * E_DIM / 4);
    split_kernel<<<(E_DIM * E_DIM / 4 + 255) / 256, 256, 0, stream>>>(
        w_out, w_out_hi, w_out_lo, E_DIM * E_DIM / 4);
    cvt_bf16_kernel<<<(SEQ * SEQ / 4 + 255) / 256, 256, 0, stream>>>(
        attn_mask, mask_bf, SEQ * SEQ / 4);

    for (int z = 0; z < 3; ++z) {
        split_kernel<<<(int)(seg / 4 / 256), 256, 0, stream>>>(
            inputs[z], bufA_hi, bufA_lo, (int)(seg / 4));
        gemm_nt_mfma<<<dim3(E_DIM / 128, MROWS / 128), 256, 0, stream>>>(
            bufA_hi, bufA_lo,
            w_in_hi + (size_t)z * E_DIM * E_DIM, w_in_lo + (size_t)z * E_DIM * E_DIM,
            b_in + z * E_DIM,
            nullptr, qkv + (size_t)z * seg,
            MROWS, E_DIM, E_DIM, (z == 2) ? 2 : 1);
    }

    attn_mfma_kernel<<<dim3(SEQ / 128, BATCH * NHEADS), 256, 0, stream>>>(
        qkv, mask_bf, kpad, ctx_hi, ctx_lo);

    gemm_nt_mfma<<<dim3(E_DIM / 128, MROWS / 128), 256, 0, stream>>>(
        ctx_hi, ctx_lo, w_out_hi, w_out_lo, b_out,
        out, nullptr, MROWS, E_DIM, E_DIM, 0);
}

// Round 6
// 532.537 us; speedup vs baseline: 3.6875x; 1.1511x over previous
//
#include <hip/hip_runtime.h>
#include <cstdint>
#include <cstddef>

#define E_DIM   1024
#define NHEADS  16
#define DHEAD   64
#define BATCH   8
#define SEQ     1024
#define MROWS   (BATCH*SEQ)   // 8192

typedef __bf16 bf16;
typedef __attribute__((ext_vector_type(8))) __bf16 bf16x8;
typedef __attribute__((ext_vector_type(4))) __bf16 bf16x4;
typedef __attribute__((ext_vector_type(4))) float f32x4;

typedef const __attribute__((address_space(1))) unsigned int gu32;
typedef __attribute__((address_space(3))) unsigned int lu32;

// ---------------------------------------------------------------------------
// split fp32 -> bf16 hi + bf16 lo
// ---------------------------------------------------------------------------
__global__ __launch_bounds__(256)
void split_kernel(const float* __restrict__ src, bf16* __restrict__ hi,
                  bf16* __restrict__ lo, int n4)
{
    int i = blockIdx.x * 256 + threadIdx.x;
    if (i >= n4) return;
    float4 x = ((const float4*)src)[i];
    bf16x4 h, l;
    h[0] = (bf16)x.x; l[0] = (bf16)(x.x - (float)h[0]);
    h[1] = (bf16)x.y; l[1] = (bf16)(x.y - (float)h[1]);
    h[2] = (bf16)x.z; l[2] = (bf16)(x.z - (float)h[2]);
    h[3] = (bf16)x.w; l[3] = (bf16)(x.w - (float)h[3]);
    ((bf16x4*)hi)[i] = h;
    ((bf16x4*)lo)[i] = l;
}

// fp32 -> bf16 (mask)
__global__ __launch_bounds__(256)
void cvt_bf16_kernel(const float* __restrict__ src, bf16* __restrict__ dst, int n4)
{
    int i = blockIdx.x * 256 + threadIdx.x;
    if (i >= n4) return;
    float4 x = ((const float4*)src)[i];
    bf16x4 h;
    h[0] = (bf16)x.x; h[1] = (bf16)x.y; h[2] = (bf16)x.z; h[3] = (bf16)x.w;
    ((bf16x4*)dst)[i] = h;
}

// ---------------------------------------------------------------------------
// MFMA GEMM, split-bf16, fused 3-term K-loop (48 MFMAs / k-step):
//   acc += Ahi.Whi + Ahi.Wlo + Alo.Whi
// mode 0: outF[m*N+n]  (fp32)
// mode 1: bf16 (hi only) scatter to (B,H,T,Dh)
// mode 2: bf16 (hi only) scatter to (B,H,Dh,T)   [transposed V]
// ---------------------------------------------------------------------------
__global__ __launch_bounds__(256)
void gemm_nt_mfma(const bf16* __restrict__ Ahi, const bf16* __restrict__ Alo,
                  const bf16* __restrict__ Whi, const bf16* __restrict__ Wlo,
                  const float* __restrict__ bias,
                  float* __restrict__ outF, bf16* __restrict__ outHi,
                  int M, int N, int K, int mode)
{
    __shared__ bf16 Ahs[128 * 32];
    __shared__ bf16 Als[128 * 32];
    __shared__ bf16 Whs[128 * 32];
    __shared__ bf16 Wls[128 * 32];

    const int tid  = threadIdx.x;
    const int lane = tid & 63;
    const int wid  = tid >> 6;
    const int wm = (wid >> 1) * 64;
    const int wn = (wid & 1) * 64;
    const int fr = lane & 15;
    const int fk = (lane >> 4) * 8;

    const int mBase = blockIdx.y * 128;
    const int nBase = blockIdx.x * 128;

    const int rowA0 = tid >> 2;
    const int colA0 = (tid & 3) * 8;

    f32x4 acc[4][4];
#pragma unroll
    for (int i = 0; i < 4; ++i)
#pragma unroll
        for (int j = 0; j < 4; ++j) acc[i][j] = (f32x4){0.f, 0.f, 0.f, 0.f};

#pragma unroll 1
    for (int k0 = 0; k0 < K; k0 += 32) {
        const size_t ga0 = (size_t)(mBase + rowA0) * K + k0 + colA0;
        const size_t ga1 = ga0 + (size_t)64 * K;
        const size_t gw0 = (size_t)(nBase + rowA0) * K + k0 + colA0;
        const size_t gw1 = gw0 + (size_t)64 * K;
        __builtin_amdgcn_global_load_lds((gu32*)(Ahi + ga0), (lu32*)&Ahs[wid * 512],        16, 0, 0);
        __builtin_amdgcn_global_load_lds((gu32*)(Ahi + ga1), (lu32*)&Ahs[2048 + wid * 512], 16, 0, 0);
        __builtin_amdgcn_global_load_lds((gu32*)(Alo + ga0), (lu32*)&Als[wid * 512],        16, 0, 0);
        __builtin_amdgcn_global_load_lds((gu32*)(Alo + ga1), (lu32*)&Als[2048 + wid * 512], 16, 0, 0);
        __builtin_amdgcn_global_load_lds((gu32*)(Whi + gw0), (lu32*)&Whs[wid * 512],        16, 0, 0);
        __builtin_amdgcn_global_load_lds((gu32*)(Whi + gw1), (lu32*)&Whs[2048 + wid * 512], 16, 0, 0);
        __builtin_amdgcn_global_load_lds((gu32*)(Wlo + gw0), (lu32*)&Wls[wid * 512],        16, 0, 0);
        __builtin_amdgcn_global_load_lds((gu32*)(Wlo + gw1), (lu32*)&Wls[2048 + wid * 512], 16, 0, 0);
        __syncthreads();

        bf16x8 afh[4], afl[4], bfh[4], bfl[4];
#pragma unroll
        for (int am = 0; am < 4; ++am) {
            afh[am] = *(const bf16x8*)&Ahs[(wm + am * 16 + fr) * 32 + fk];
            afl[am] = *(const bf16x8*)&Als[(wm + am * 16 + fr) * 32 + fk];
        }
#pragma unroll
        for (int bn = 0; bn < 4; ++bn) {
            bfh[bn] = *(const bf16x8*)&Whs[(wn + bn * 16 + fr) * 32 + fk];
            bfl[bn] = *(const bf16x8*)&Wls[(wn + bn * 16 + fr) * 32 + fk];
        }
#pragma unroll
        for (int am = 0; am < 4; ++am)
#pragma unroll
            for (int bn = 0; bn < 4; ++bn) {
                acc[am][bn] = __builtin_amdgcn_mfma_f32_16x16x32_bf16(afh[am], bfh[bn], acc[am][bn], 0, 0, 0);
                acc[am][bn] = __builtin_amdgcn_mfma_f32_16x16x32_bf16(afh[am], bfl[bn], acc[am][bn], 0, 0, 0);
                acc[am][bn] = __builtin_amdgcn_mfma_f32_16x16x32_bf16(afl[am], bfh[bn], acc[am][bn], 0, 0, 0);
            }
        __syncthreads();
    }

    const int drow = (lane >> 4) * 4;
    const int dcol = lane & 15;
#pragma unroll
    for (int bn = 0; bn < 4; ++bn) {
        const int col = nBase + wn + bn * 16 + dcol;
        const float bv = bias[col];
#pragma unroll
        for (int am = 0; am < 4; ++am) {
#pragma unroll
            for (int r = 0; r < 4; ++r) {
                const int row = mBase + wm + am * 16 + drow + r;
                const float v = acc[am][bn][r] + bv;
                if (mode == 0) {
                    outF[(size_t)row * N + col] = v;
                } else {
                    const int b = row >> 10, t = row & 1023;
                    const int h = col >> 6,  d = col & 63;
                    size_t idx;
                    if (mode == 1)
                        idx = (((size_t)(b * NHEADS + h)) * SEQ + t) * DHEAD + d;
                    else
                        idx = (((size_t)(b * NHEADS + h)) * DHEAD + d) * SEQ + t;
                    outHi[idx] = (bf16)v;
                }
            }
        }
    }
}

// ---------------------------------------------------------------------------
// MFMA flash attention, single-bf16, S^T formulation, q-tile 64,
// DOUBLE-BUFFERED K/V^T staging with distance-1 prefetch:
//   iter kt: issue loads(kt+1 -> buf^1), compute on buf, barrier.
// The barrier's vmcnt drain lands one compute-phase after issue -> latency
// mostly hidden inside the block; 2048 blocks give cross-block overlap.
// ---------------------------------------------------------------------------
__global__ __launch_bounds__(256)
void attn_mfma_kernel(const bf16* __restrict__ qkv,
                      const bf16* __restrict__ mask_bf,
                      const unsigned char* __restrict__ kpad,
                      bf16* __restrict__ ctx_hi, bf16* __restrict__ ctx_lo)
{
    __shared__ bf16 Ks [2][4096];               // 16 KB
    __shared__ bf16 Vts[2][4096];               // 16 KB
    __shared__ float kaddf[1024];               // 4 KB
    __shared__ bf16 Pn[4][16 * 72];             // 9 KB

    const int tid  = threadIdx.x;
    const int lane = tid & 63;
    const int wid  = tid >> 6;
    const int c16  = lane & 15;
    const int quad = lane >> 4;

    const int qt = blockIdx.x;             // 0..15
    const int bh = blockIdx.y;             // 0..127
    const int b = bh >> 4, h = bh & 15;

    const size_t seg = (size_t)MROWS * E_DIM;
    const size_t headoff = (size_t)bh * SEQ * DHEAD;
    const bf16* Q_g  = qkv + headoff;
    const bf16* K_g  = qkv + seg + headoff;
    const bf16* Vt_g = qkv + 2 * seg + headoff;   // [d][t]

    const int qglob = qt * 64 + wid * 16 + c16;

    // Q B-frags, resident for whole kernel
    bf16x8 qf[2];
#pragma unroll
    for (int ks = 0; ks < 2; ++ks)
        qf[ks] = *(const bf16x8*)&Q_g[(size_t)qglob * DHEAD + quad * 8 + ks * 32];

    for (int i = tid; i < SEQ; i += 256)
        kaddf[i] = kpad[(size_t)b * SEQ + i] ? -1e30f : 0.f;

    float m_i = -1e30f, l_i = 0.f;
    f32x4 oacc[4];
#pragma unroll
    for (int dt = 0; dt < 4; ++dt) oacc[dt] = (f32x4){0.f, 0.f, 0.f, 0.f};

    const int row0 = tid >> 3,         c0 = (tid & 7) ^ (row0 & 7);
    const int row1 = (tid + 256) >> 3, c1 = ((tid + 256) & 7) ^ (row1 & 7);

    // stage K tile + V^T tile for key-tile kt into buffer bi
    auto stage = [&](int kt, int bi) {
        const int ktb = kt * 64;
        const size_t k0 = (size_t)(ktb + row0) * DHEAD + c0 * 8;
        const size_t k1 = (size_t)(ktb + row1) * DHEAD + c1 * 8;
        const size_t v0 = (size_t)row0 * SEQ + ktb + c0 * 8;
        const size_t v1 = (size_t)row1 * SEQ + ktb + c1 * 8;
        __builtin_amdgcn_global_load_lds((gu32*)(K_g + k0),  (lu32*)&Ks [bi][wid * 512],        16, 0, 0);
        __builtin_amdgcn_global_load_lds((gu32*)(K_g + k1),  (lu32*)&Ks [bi][2048 + wid * 512], 16, 0, 0);
        __builtin_amdgcn_global_load_lds((gu32*)(Vt_g + v0), (lu32*)&Vts[bi][wid * 512],        16, 0, 0);
        __builtin_amdgcn_global_load_lds((gu32*)(Vt_g + v1), (lu32*)&Vts[bi][2048 + wid * 512], 16, 0, 0);
    };

    stage(0, 0);
    __syncthreads();   // drain prefetch 0 + kaddf visible

#pragma unroll 1
    for (int kt = 0; kt < 16; ++kt) {
        const int cur = kt & 1;
        const int ktb = kt * 64;
        if (kt < 15) stage(kt + 1, cur ^ 1);

        // mask loads (bf16, L2-resident), overlap with MFMA
        bf16x4 mvh[4];
#pragma unroll
        for (int st = 0; st < 4; ++st)
            mvh[st] = *(const bf16x4*)&mask_bf[(size_t)qglob * SEQ + ktb + st * 16 + quad * 4];

        // ---- S^T = K.Q^T ----
        f32x4 sacc[4];
#pragma unroll
        for (int st = 0; st < 4; ++st) sacc[st] = (f32x4){0.f, 0.f, 0.f, 0.f};
#pragma unroll
        for (int st = 0; st < 4; ++st) {
            const int row = st * 16 + c16;
            const int sw  = row & 7;
#pragma unroll
            for (int ks = 0; ks < 2; ++ks) {
                const int cp = ((quad + ks * 4) ^ sw);
                bf16x8 kh = *(const bf16x8*)&Ks[cur][(row * 8 + cp) * 8];
                sacc[st] = __builtin_amdgcn_mfma_f32_16x16x32_bf16(kh, qf[ks], sacc[st], 0, 0, 0);
            }
        }

        // ---- online softmax over keys ----
        float s[16], tmax = -1e30f;
#pragma unroll
        for (int st = 0; st < 4; ++st) {
            float4 ka = *(const float4*)&kaddf[ktb + st * 16 + quad * 4];
#pragma unroll
            for (int r = 0; r < 4; ++r) {
                float kav = (r == 0) ? ka.x : (r == 1) ? ka.y : (r == 2) ? ka.z : ka.w;
                float sv = sacc[st][r] * 0.125f + (float)mvh[st][r] + kav;
                s[st * 4 + r] = sv;
                tmax = fmaxf(tmax, sv);
            }
        }
        tmax = fmaxf(tmax, __shfl_xor(tmax, 16, 64));
        tmax = fmaxf(tmax, __shfl_xor(tmax, 32, 64));
        const float mnew  = fmaxf(m_i, tmax);
        const float alpha = __expf(m_i - mnew);
        float p[16], ps = 0.f;
#pragma unroll
        for (int i = 0; i < 16; ++i) { p[i] = __expf(s[i] - mnew); ps += p[i]; }
        ps += __shfl_xor(ps, 16, 64);
        ps += __shfl_xor(ps, 32, 64);
        l_i = l_i * alpha + ps;
        m_i = mnew;

        // ---- P (bf16) via wave-private LDS transform ----
#pragma unroll
        for (int st = 0; st < 4; ++st) {
            bf16x4 ph;
#pragma unroll
            for (int r = 0; r < 4; ++r) ph[r] = (bf16)p[st * 4 + r];
            *(bf16x4*)&Pn[wid][c16 * 72 + st * 16 + quad * 4] = ph;
        }
        bf16x8 pf[2];
#pragma unroll
        for (int ks = 0; ks < 2; ++ks)
            pf[ks] = *(const bf16x8*)&Pn[wid][c16 * 72 + ks * 32 + quad * 8];

        // ---- O^T += V^T.P ----
#pragma unroll
        for (int dt = 0; dt < 4; ++dt) {
#pragma unroll
            for (int r = 0; r < 4; ++r) oacc[dt][r] *= alpha;
            const int row = dt * 16 + c16;
            const int sw  = row & 7;
#pragma unroll
            for (int ks = 0; ks < 2; ++ks) {
                const int cp = ((quad + ks * 4) ^ sw);
                bf16x8 vh = *(const bf16x8*)&Vts[cur][(row * 8 + cp) * 8];
                oacc[dt] = __builtin_amdgcn_mfma_f32_16x16x32_bf16(vh, pf[ks], oacc[dt], 0, 0, 0);
            }
        }

        __syncthreads();   // drains prefetch(kt+1); guards buffer reuse
    }

    // ---- epilogue: split O into hi/lo for the out-projection ----
    const float invl = 1.0f / l_i;
#pragma unroll
    for (int dt = 0; dt < 4; ++dt) {
        bf16x4 oh, ol;
#pragma unroll
        for (int r = 0; r < 4; ++r) {
            float v = oacc[dt][r] * invl;
            oh[r] = (bf16)v;
            ol[r] = (bf16)(v - (float)oh[r]);
        }
        size_t idx = ((size_t)b * SEQ + qglob) * E_DIM + h * DHEAD + dt * 16 + quad * 4;
        *(bf16x4*)&ctx_hi[idx] = oh;
        *(bf16x4*)&ctx_lo[idx] = ol;
    }
}

// ---------------------------------------------------------------------------
extern "C" void kernel_launch(void* const* d_in, const int* in_sizes, int n_in,
                              void* d_out, int out_size, void* d_ws, size_t ws_size,
                              hipStream_t stream)
{
    const float* inputs[3] = { (const float*)d_in[0], (const float*)d_in[1],
                               (const float*)d_in[2] };
    const unsigned char* kpad = (const unsigned char*)d_in[3];
    const float* attn_mask = (const float*)d_in[4];
    const float* w_in  = (const float*)d_in[5];
    const float* b_in  = (const float*)d_in[6];
    const float* w_out = (const float*)d_in[7];
    const float* b_out = (const float*)d_in[8];
    float* out = (float*)d_out;

    char* ws = (char*)d_ws;
    const size_t MB = 1024 * 1024;
    bf16* bufA_hi  = (bf16*)(ws + 0 * MB);    // 16MB per-z reuse
    bf16* bufA_lo  = (bf16*)(ws + 16 * MB);   // 16MB
    bf16* w_in_hi  = (bf16*)(ws + 32 * MB);   // 6MB
    bf16* w_in_lo  = (bf16*)(ws + 38 * MB);   // 6MB
    bf16* w_out_hi = (bf16*)(ws + 44 * MB);   // 2MB
    bf16* w_out_lo = (bf16*)(ws + 46 * MB);   // 2MB
    bf16* qkv      = (bf16*)(ws + 48 * MB);   // 48MB (Q,K,Vt bf16)
    bf16* mask_bf  = (bf16*)(ws + 96 * MB);   // 2MB
    bf16* ctx_hi   = (bf16*)(ws + 0 * MB);    // reuse bufA after QKV
    bf16* ctx_lo   = (bf16*)(ws + 16 * MB);

    const size_t seg = (size_t)MROWS * E_DIM;

    split_kernel<<<(3 * E_DIM * E_DIM / 4 + 255) / 256, 256, 0, stream>>>(
        w_in, w_in_hi, w_in_lo, 3 * E_DIM * E_DIM / 4);
    split_kernel<<<(E_DIM * E_DIM / 4 + 255) / 256, 256, 0, stream>>>(
        w_out, w_out_hi, w_out_lo, E_DIM * E_DIM / 4);
    cvt_bf16_kernel<<<(SEQ * SEQ / 4 + 255) / 256, 256, 0, stream>>>(
        attn_mask, mask_bf, SEQ * SEQ / 4);

    for (int z = 0; z < 3; ++z) {
        split_kernel<<<(int)(seg / 4 / 256), 256, 0, stream>>>(
            inputs[z], bufA_hi, bufA_lo, (int)(seg / 4));
        gemm_nt_mfma<<<dim3(E_DIM / 128, MROWS / 128), 256, 0, stream>>>(
            bufA_hi, bufA_lo,
            w_in_hi + (size_t)z * E_DIM * E_DIM, w_in_lo + (size_t)z * E_DIM * E_DIM,
            b_in + z * E_DIM,
            nullptr, qkv + (size_t)z * seg,
            MROWS, E_DIM, E_DIM, (z == 2) ? 2 : 1);
    }

    attn_mfma_kernel<<<dim3(SEQ / 64, BATCH * NHEADS), 256, 0, stream>>>(
        qkv, mask_bf, kpad, ctx_hi, ctx_lo);

    gemm_nt_mfma<<<dim3(E_DIM / 128, MROWS / 128), 256, 0, stream>>>(
        ctx_hi, ctx_lo, w_out_hi, w_out_lo, b_out,
        out, nullptr, MROWS, E_DIM, E_DIM, 0);
}